// Round 1
// baseline (3453.100 us; speedup 1.0000x reference)
//
#include <hip/hip_runtime.h>
#include <math.h>

#define BB   32
#define DIN  100
#define HH   256
#define NLAY 4
#define NH   32
#define LL   4096
#define LC   128
#define NC   32
#define HL   (HH*LL)   // 1048576
#define BLn  (BB*LL)   // 131072
#define BCC  (BB*NC)   // 1024

// ---------------- encoder: h[b][o][hw] = sum_i x[b][i] * ew[i][o][hw] ----------------
__global__ __launch_bounds__(256) void k_enc(const float* __restrict__ x,
                                             const float* __restrict__ ew,
                                             float* __restrict__ hbuf) {
    __shared__ __align__(16) float xs[DIN*BB];   // xs[i][b]
    int tid = threadIdx.x;
    for (int idx = tid; idx < DIN*BB; idx += 256) {
        int b = idx & 31, i = idx >> 5;
        xs[i*BB + b] = x[b*DIN + i];
    }
    __syncthreads();
    int gid0 = (blockIdx.x*256 + tid) * 4;   // 4 consecutive (o,hw) indices
    float accv[BB][4];
    #pragma unroll
    for (int b = 0; b < BB; b++) { accv[b][0]=0.f; accv[b][1]=0.f; accv[b][2]=0.f; accv[b][3]=0.f; }
    for (int i = 0; i < DIN; i++) {
        float4 wv = *reinterpret_cast<const float4*>(&ew[(size_t)i*HL + gid0]);
        float wvv[4] = {wv.x, wv.y, wv.z, wv.w};
        #pragma unroll
        for (int b4 = 0; b4 < 8; b4++) {
            float4 xv = *reinterpret_cast<const float4*>(&xs[i*BB + b4*4]);
            float xc[4] = {xv.x, xv.y, xv.z, xv.w};
            #pragma unroll
            for (int q = 0; q < 4; q++) {
                int b = b4*4 + q;
                accv[b][0] = fmaf(xc[q], wvv[0], accv[b][0]);
                accv[b][1] = fmaf(xc[q], wvv[1], accv[b][1]);
                accv[b][2] = fmaf(xc[q], wvv[2], accv[b][2]);
                accv[b][3] = fmaf(xc[q], wvv[3], accv[b][3]);
            }
        }
    }
    #pragma unroll
    for (int b = 0; b < BB; b++) {
        float4 o = make_float4(accv[b][0], accv[b][1], accv[b][2], accv[b][3]);
        *reinterpret_cast<float4*>(&hbuf[(size_t)b*HL + gid0]) = o;
    }
}

// ---------------- per-layer parameter precompute ----------------
__global__ __launch_bounds__(256) void k_prep1(const float* __restrict__ ldt,
        const float* __restrict__ Cp, const float* __restrict__ lAr,
        const float* __restrict__ Aimp, int layer,
        float* __restrict__ pdta, float* __restrict__ pwlc, float* __restrict__ pcd2) {
    int t = blockIdx.x*256 + threadIdx.x;   // 8192 = h*32+n
    int h = t >> 5, n = t & 31;
    float dt  = expf(ldt[layer*HH + h]);
    float are = -expf(lAr[(layer*HH + h)*NH + n]);
    float aim = Aimp[(layer*HH + h)*NH + n];
    float dre = are*dt, dimg = aim*dt;
    float er = expf(dre);
    float s, c; sincosf(dimg, &s, &c);
    float wre = er*c, wim = er*s;
    // (w-1)/A
    float den = are*are + aim*aim;
    float nre = wre - 1.f, nim = wim;
    float qre = (nre*are + nim*aim)/den;
    float qim = (nim*are - nre*aim)/den;
    float cre = Cp[((layer*HH + h)*NH + n)*2 + 0];
    float cim = Cp[((layer*HH + h)*NH + n)*2 + 1];
    float dcr = cre*qre - cim*qim;
    float dci = cre*qim + cim*qre;
    pcd2[t*2+0] = 2.f*dcr;  pcd2[t*2+1] = 2.f*dci;   // Cd2 = 2*C'
    pdta[t*2+0] = dre;      pdta[t*2+1] = dimg;
    float erl = expf(dre*(float)LC);
    float sl, cl; sincosf(dimg*(float)LC, &sl, &cl);
    pwlc[t*2+0] = erl*cl;   pwlc[t*2+1] = erl*sl;     // w^Lc
}

// kker[h][m] = Re( sum_n Cd2_n * w_n^m ),  m=0..Lc-1
__global__ __launch_bounds__(256) void k_kker(const float* __restrict__ pdta,
        const float* __restrict__ pcd2, float* __restrict__ kk) {
    int g = blockIdx.x*256 + threadIdx.x;   // 32768
    int m = g & 127, h = g >> 7;
    float fm = (float)m;
    float acc = 0.f;
    for (int n = 0; n < NH; n++) {
        float dre = pdta[(h*NH+n)*2], dimg = pdta[(h*NH+n)*2+1];
        float er = expf(dre*fm);
        float s, c; sincosf(dimg*fm, &s, &c);
        float dcr = pcd2[(h*NH+n)*2], dci = pcd2[(h*NH+n)*2+1];
        acc += dcr*er*c - dci*er*s;
    }
    kk[g] = acc;
}

// A_stateT[h][m][r] : r=2n -> Re(w^(Lc-1-m)), r=2n+1 -> Im(w^(Lc-1-m))
__global__ __launch_bounds__(256) void k_bldA(const float* __restrict__ pdta,
                                              float* __restrict__ AstT) {
    int g = blockIdx.x*256 + threadIdx.x;   // 256*128*32
    int n = g & 31; int m = (g >> 5) & 127; int h = g >> 12;
    float e = (float)(LC - 1 - m);
    float dre = pdta[(h*NH+n)*2], dimg = pdta[(h*NH+n)*2+1];
    float er = expf(dre*e);
    float s, c; sincosf(dimg*e, &s, &c);
    AstT[h*(LC*64) + m*64 + 2*n + 0] = er*c;
    AstT[h*(LC*64) + m*64 + 2*n + 1] = er*s;
}

// A_convT[h][k][j]: k<128 -> Toeplitz kker[j-k]; k=128+2n -> Re(w^(j+1)); k=128+2n+1 -> -Im(w^(j+1))
__global__ __launch_bounds__(256) void k_bldC(const float* __restrict__ pdta,
        const float* __restrict__ kk, float* __restrict__ AcvT) {
    int g = blockIdx.x*256 + threadIdx.x;   // 256*192*128
    int j = g & 127; int rem = g >> 7; int r = rem % 192; int h = rem / 192;
    float v;
    if (r < 128) {
        v = (j >= r) ? kk[h*128 + (j - r)] : 0.f;
    } else {
        int t = r - 128; int n = t >> 1;
        float dre = pdta[(h*NH+n)*2], dimg = pdta[(h*NH+n)*2+1];
        float e = (float)(j + 1);
        float er = expf(dre*e);
        float s, c; sincosf(dimg*e, &s, &c);
        v = (t & 1) ? (-er*s) : (er*c);
    }
    AcvT[h*(192*128) + r*128 + j] = v;
}

// ---------------- GEMM-A: F[h](64 x 1024) = Wm(64 x 128) * U(128 x 1024) ----------------
__global__ __launch_bounds__(256) void k_gA(const float* __restrict__ AstT,
        const float* __restrict__ hbuf, float* __restrict__ FT) {
    __shared__ __align__(16) float Al[32][64];
    __shared__ __align__(16) float Bl[32][132];
    int ct = blockIdx.x, h = blockIdx.y;
    int tid = threadIdx.x;
    int tr = tid & 31, tc = tid >> 5;
    float acc[2][16];
    #pragma unroll
    for (int i = 0; i < 2; i++)
        #pragma unroll
        for (int j = 0; j < 16; j++) acc[i][j] = 0.f;
    const float* Ab = AstT + h*(LC*64);
    for (int kb = 0; kb < 4; kb++) {
        int k0 = kb*32;
        { int r = tid & 63, kq = tid >> 6;
          #pragma unroll
          for (int j = 0; j < 8; j++) { int k = kq*8 + j; Al[k][r] = Ab[(k0+k)*64 + r]; } }
        { int k = tid & 31;
          #pragma unroll
          for (int j = 0; j < 16; j++) {
              int col = (tid >> 5) + 8*j;
              int gcol = ct*128 + col;
              int b = gcol & 31, c = gcol >> 5;
              Bl[k][col] = hbuf[b*HL + h*LL + c*LC + k0 + k];
          } }
        __syncthreads();
        #pragma unroll 8
        for (int k = 0; k < 32; k++) {
            float a0 = Al[k][tr], a1 = Al[k][tr+32];
            float bv[16];
            *(float4*)&bv[0]  = *(float4*)&Bl[k][tc*16+0];
            *(float4*)&bv[4]  = *(float4*)&Bl[k][tc*16+4];
            *(float4*)&bv[8]  = *(float4*)&Bl[k][tc*16+8];
            *(float4*)&bv[12] = *(float4*)&Bl[k][tc*16+12];
            #pragma unroll
            for (int j = 0; j < 16; j++) {
                acc[0][j] = fmaf(a0, bv[j], acc[0][j]);
                acc[1][j] = fmaf(a1, bv[j], acc[1][j]);
            }
        }
        __syncthreads();
    }
    float* F0 = FT + h*(64*BCC) + tr*BCC + ct*128 + tc*16;
    float* F1 = F0 + 32*BCC;
    *(float4*)&F0[0]  = make_float4(acc[0][0], acc[0][1], acc[0][2], acc[0][3]);
    *(float4*)&F0[4]  = make_float4(acc[0][4], acc[0][5], acc[0][6], acc[0][7]);
    *(float4*)&F0[8]  = make_float4(acc[0][8], acc[0][9], acc[0][10], acc[0][11]);
    *(float4*)&F0[12] = make_float4(acc[0][12], acc[0][13], acc[0][14], acc[0][15]);
    *(float4*)&F1[0]  = make_float4(acc[1][0], acc[1][1], acc[1][2], acc[1][3]);
    *(float4*)&F1[4]  = make_float4(acc[1][4], acc[1][5], acc[1][6], acc[1][7]);
    *(float4*)&F1[8]  = make_float4(acc[1][8], acc[1][9], acc[1][10], acc[1][11]);
    *(float4*)&F1[12] = make_float4(acc[1][12], acc[1][13], acc[1][14], acc[1][15]);
}

// ---------------- chunk-prefix scan: F -> T in place ----------------
__global__ __launch_bounds__(256) void k_scan(const float* __restrict__ pwlc,
        const float* __restrict__ pcd2, float* __restrict__ FT) {
    int t = blockIdx.x*256 + threadIdx.x;   // 262144 = ((h*32)+n)*32+b
    int b = t & 31, n = (t >> 5) & 31, h = t >> 10;
    float wlr = pwlc[(h*NH+n)*2], wli = pwlc[(h*NH+n)*2+1];
    float cr  = pcd2[(h*NH+n)*2], ci  = pcd2[(h*NH+n)*2+1];
    float sr = 0.f, si = 0.f;
    float* Fre = FT + h*(64*BCC) + (2*n)*BCC + b;
    float* Fim = Fre + BCC;
    for (int c = 0; c < NC; c++) {
        float fr = Fre[c*32], fi = Fim[c*32];
        Fre[c*32] = cr*sr - ci*si;             // T = Cd2 * S
        Fim[c*32] = cr*si + ci*sr;
        float nsr = fmaf(wlr, sr, fmaf(-wli, si, fr));   // S = wLc*S + F
        si = fmaf(wlr, si, fmaf(wli, sr, fi));
        sr = nsr;
    }
}

// ---------------- GEMM-B: y[h](128 x 1024) = Acv(128 x 192) * [U;T](192 x 1024), fused Dskip+GELU ----------------
__global__ __launch_bounds__(256) void k_gB(const float* __restrict__ AcvT,
        const float* __restrict__ hbuf, const float* __restrict__ FT,
        const float* __restrict__ Dsk, int layer, float* __restrict__ Y) {
    __shared__ __align__(16) float Al[32][132];
    __shared__ __align__(16) float Bl[32][132];
    int ct = blockIdx.x, h = blockIdx.y;
    int tid = threadIdx.x;
    int tr = tid & 31, tc = tid >> 5;
    float acc[4][16];
    #pragma unroll
    for (int i = 0; i < 4; i++)
        #pragma unroll
        for (int j = 0; j < 16; j++) acc[i][j] = 0.f;
    const float* Ab = AcvT + h*(192*128);
    for (int kb = 0; kb < 6; kb++) {
        int k0 = kb*32;
        { int r = tid & 127, kq = tid >> 7;
          #pragma unroll
          for (int j = 0; j < 16; j++) { int k = kq*16 + j; Al[k][r] = Ab[(k0+k)*128 + r]; } }
        if (kb < 4) {
            int k = tid & 31;
            #pragma unroll
            for (int j = 0; j < 16; j++) {
                int col = (tid >> 5) + 8*j;
                int gcol = ct*128 + col;
                int b = gcol & 31, c = gcol >> 5;
                Bl[k][col] = hbuf[b*HL + h*LL + c*LC + k0 + k];
            }
        } else {
            int col = tid & 127, kq = tid >> 7;
            #pragma unroll
            for (int j = 0; j < 16; j++) {
                int k = kq*16 + j;
                Bl[k][col] = FT[h*(64*BCC) + (k0 - 128 + k)*BCC + ct*128 + col];
            }
        }
        __syncthreads();
        #pragma unroll 4
        for (int k = 0; k < 32; k++) {
            float aa[4];
            *(float4*)&aa[0] = *(float4*)&Al[k][tr*4];
            float bv[16];
            *(float4*)&bv[0]  = *(float4*)&Bl[k][tc*16+0];
            *(float4*)&bv[4]  = *(float4*)&Bl[k][tc*16+4];
            *(float4*)&bv[8]  = *(float4*)&Bl[k][tc*16+8];
            *(float4*)&bv[12] = *(float4*)&Bl[k][tc*16+12];
            #pragma unroll
            for (int i = 0; i < 4; i++)
                #pragma unroll
                for (int j = 0; j < 16; j++)
                    acc[i][j] = fmaf(aa[i], bv[j], acc[i][j]);
        }
        __syncthreads();
    }
    float dsk = Dsk[layer*HH + h];
    #pragma unroll
    for (int j = 0; j < 16; j++) {
        int gcol = ct*128 + tc*16 + j;
        int b = gcol & 31, c = gcol >> 5;
        float uu[4];
        *(float4*)&uu[0] = *(const float4*)&hbuf[b*HL + h*LL + c*LC + tr*4];
        float ov[4];
        #pragma unroll
        for (int i = 0; i < 4; i++) {
            float yv = acc[i][j] + dsk*uu[i];
            ov[i] = 0.5f*yv*(1.f + erff(yv*0.70710678118f));   // exact GELU
        }
        *(float4*)&Y[h*BLn + gcol*128 + tr*4] = make_float4(ov[0], ov[1], ov[2], ov[3]);
    }
}

// ---------------- GEMM-C: z(512 x 131072) = W * Y, fused bias+GLU+residual (in-place on hbuf) ----------------
__global__ __launch_bounds__(256) void k_gC(const float* __restrict__ Wp,
        const float* __restrict__ outb, const float* __restrict__ Y,
        float* __restrict__ hbuf) {
    __shared__ __align__(16) float Al[32][132];
    __shared__ __align__(16) float Bl[32][132];
    int mt = blockIdx.x, ct = blockIdx.y;
    int tid = threadIdx.x;
    int tr = tid & 31, tc = tid >> 5;
    float acc[4][16];
    #pragma unroll
    for (int i = 0; i < 4; i++)
        #pragma unroll
        for (int j = 0; j < 16; j++) acc[i][j] = 0.f;
    for (int kb = 0; kb < 8; kb++) {
        int k0 = kb*32;
        { int r = tid & 127, kq = tid >> 7;
          int o = mt*64 + (r & 63) + ((r >= 64) ? 256 : 0);
          const float* wrow = Wp + o*HH + k0 + kq*16;
          float wv[16];
          *(float4*)&wv[0]  = *(const float4*)&wrow[0];
          *(float4*)&wv[4]  = *(const float4*)&wrow[4];
          *(float4*)&wv[8]  = *(const float4*)&wrow[8];
          *(float4*)&wv[12] = *(const float4*)&wrow[12];
          #pragma unroll
          for (int j = 0; j < 16; j++) Al[kq*16 + j][r] = wv[j];
        }
        { int col = tid & 127, kq = tid >> 7;
          #pragma unroll
          for (int j = 0; j < 16; j++) {
              int k = kq*16 + j;
              Bl[k][col] = Y[(k0 + k)*BLn + ct*128 + col];
          } }
        __syncthreads();
        #pragma unroll 4
        for (int k = 0; k < 32; k++) {
            float2 alo = *(float2*)&Al[k][tr*2];
            float2 ahi = *(float2*)&Al[k][64 + tr*2];
            float bv[16];
            *(float4*)&bv[0]  = *(float4*)&Bl[k][tc*16+0];
            *(float4*)&bv[4]  = *(float4*)&Bl[k][tc*16+4];
            *(float4*)&bv[8]  = *(float4*)&Bl[k][tc*16+8];
            *(float4*)&bv[12] = *(float4*)&Bl[k][tc*16+12];
            #pragma unroll
            for (int j = 0; j < 16; j++) {
                acc[0][j] = fmaf(alo.x, bv[j], acc[0][j]);
                acc[1][j] = fmaf(alo.y, bv[j], acc[1][j]);
                acc[2][j] = fmaf(ahi.x, bv[j], acc[2][j]);
                acc[3][j] = fmaf(ahi.y, bv[j], acc[3][j]);
            }
        }
        __syncthreads();
    }
    int b = ct & 31, c = ct >> 5;
    #pragma unroll
    for (int i = 0; i < 2; i++) {
        int op = mt*64 + tr*2 + i;
        float ba = outb[op], bb = outb[op + 256];
        #pragma unroll
        for (int q4 = 0; q4 < 4; q4++) {
            int j0 = tc*16 + q4*4;
            float* hp = &hbuf[b*HL + op*LL + c*LC + j0];
            float hv[4];
            *(float4*)&hv[0] = *(float4*)hp;
            #pragma unroll
            for (int w = 0; w < 4; w++) {
                float za = acc[i][q4*4 + w] + ba;
                float zb = acc[2 + i][q4*4 + w] + bb;
                float sig = 1.f/(1.f + expf(-zb));
                hv[w] = hv[w] + za*sig;
            }
            *(float4*)hp = *(float4*)&hv[0];
        }
    }
}

// ---------------- decoder: out[b][l] = db + sum_h dw[h]*hbuf[b][h][l] ----------------
__global__ __launch_bounds__(256) void k_dec(const float* __restrict__ hbuf,
        const float* __restrict__ dw, const float* __restrict__ db,
        float* __restrict__ out) {
    __shared__ float wsm[HH];
    int tid = threadIdx.x;
    wsm[tid] = dw[tid];
    __syncthreads();
    int g = (blockIdx.x*256 + tid)*4;   // over B*L
    int b = g >> 12, l = g & 4095;
    float a0 = db[0], a1 = a0, a2 = a0, a3 = a0;
    for (int hh = 0; hh < HH; hh++) {
        float w = wsm[hh];
        float4 hv = *(const float4*)&hbuf[b*HL + hh*LL + l];
        a0 = fmaf(w, hv.x, a0);
        a1 = fmaf(w, hv.y, a1);
        a2 = fmaf(w, hv.z, a2);
        a3 = fmaf(w, hv.w, a3);
    }
    *(float4*)&out[g] = make_float4(a0, a1, a2, a3);
}

extern "C" void kernel_launch(void* const* d_in, const int* in_sizes, int n_in,
                              void* d_out, int out_size, void* d_ws, size_t ws_size,
                              hipStream_t stream) {
    (void)in_sizes; (void)n_in; (void)out_size; (void)ws_size;
    const float* x    = (const float*)d_in[0];
    const float* ew   = (const float*)d_in[1];
    const float* ldt  = (const float*)d_in[2];
    const float* Cp   = (const float*)d_in[3];
    const float* lAr  = (const float*)d_in[4];
    const float* Aimp = (const float*)d_in[5];
    const float* Dsk  = (const float*)d_in[6];
    const float* outw = (const float*)d_in[7];
    const float* outb = (const float*)d_in[8];
    const float* dw   = (const float*)d_in[9];
    const float* db   = (const float*)d_in[10];

    float* ws   = (float*)d_ws;
    float* hbuf = ws;                      // 33,554,432 f32
    float* Y    = ws + 33554432UL;         // 33,554,432
    float* FT   = ws + 67108864UL;         // 16,777,216
    float* AstT = ws + 83886080UL;         //  2,097,152
    float* AcvT = ws + 85983232UL;         //  6,291,456
    float* kk   = ws + 92274688UL;         //     32,768
    float* pdta = ws + 92307456UL;         //     16,384
    float* pwlc = ws + 92323840UL;         //     16,384
    float* pcd2 = ws + 92340224UL;         //     16,384  (total ~369.4 MB)

    k_enc<<<1024, 256, 0, stream>>>(x, ew, hbuf);
    for (int layer = 0; layer < NLAY; layer++) {
        k_prep1<<<32, 256, 0, stream>>>(ldt, Cp, lAr, Aimp, layer, pdta, pwlc, pcd2);
        k_kker<<<128, 256, 0, stream>>>(pdta, pcd2, kk);
        k_bldA<<<4096, 256, 0, stream>>>(pdta, AstT);
        k_bldC<<<24576, 256, 0, stream>>>(pdta, kk, AcvT);
        k_gA<<<dim3(8, 256), 256, 0, stream>>>(AstT, hbuf, FT);
        k_scan<<<1024, 256, 0, stream>>>(pwlc, pcd2, FT);
        k_gB<<<dim3(8, 256), 256, 0, stream>>>(AcvT, hbuf, FT, Dsk, layer, Y);
        k_gC<<<dim3(4, 1024), 256, 0, stream>>>(outw + layer*512*HH, outb + layer*512, Y, hbuf);
    }
    k_dec<<<128, 256, 0, stream>>>(hbuf, dw, db, (float*)d_out);
}

// Round 2
// 1941.788 us; speedup vs baseline: 1.7783x; 1.7783x over previous
//
#include <hip/hip_runtime.h>
#include <math.h>

#define BB   32
#define DIN  100
#define HH   256
#define NLAY 4
#define NH   32
#define LL   4096
#define LC   128
#define NC   32
#define HL   (HH*LL)   // 1048576
#define BLn  (BB*LL)   // 131072

typedef __attribute__((ext_vector_type(8))) short s8v;
typedef __attribute__((ext_vector_type(4))) float f4v;

__device__ inline unsigned short f2b(float x) {
    unsigned int u = __float_as_uint(x);
    unsigned int r = (u + 0x7fffu + ((u >> 16) & 1u)) >> 16;
    return (unsigned short)r;
}

// ---------------- encoder: h[b][o][hw] = sum_i x[b][i] * ew[i][o][hw] ----------------
__global__ __launch_bounds__(256) void k_enc(const float* __restrict__ x,
                                             const float* __restrict__ ew,
                                             float* __restrict__ hbuf) {
    __shared__ __align__(16) float xs[DIN*BB];
    int tid = threadIdx.x;
    for (int idx = tid; idx < DIN*BB; idx += 256) {
        int b = idx & 31, i = idx >> 5;
        xs[i*BB + b] = x[b*DIN + i];
    }
    __syncthreads();
    int gid0 = (blockIdx.x*256 + tid) * 4;
    float accv[BB][4];
    #pragma unroll
    for (int b = 0; b < BB; b++) { accv[b][0]=0.f; accv[b][1]=0.f; accv[b][2]=0.f; accv[b][3]=0.f; }
    for (int i = 0; i < DIN; i++) {
        float4 wv = *reinterpret_cast<const float4*>(&ew[(size_t)i*HL + gid0]);
        float wvv[4] = {wv.x, wv.y, wv.z, wv.w};
        #pragma unroll
        for (int b4 = 0; b4 < 8; b4++) {
            float4 xv = *reinterpret_cast<const float4*>(&xs[i*BB + b4*4]);
            float xc[4] = {xv.x, xv.y, xv.z, xv.w};
            #pragma unroll
            for (int q = 0; q < 4; q++) {
                int b = b4*4 + q;
                accv[b][0] = fmaf(xc[q], wvv[0], accv[b][0]);
                accv[b][1] = fmaf(xc[q], wvv[1], accv[b][1]);
                accv[b][2] = fmaf(xc[q], wvv[2], accv[b][2]);
                accv[b][3] = fmaf(xc[q], wvv[3], accv[b][3]);
            }
        }
    }
    #pragma unroll
    for (int b = 0; b < BB; b++) {
        float4 o = make_float4(accv[b][0], accv[b][1], accv[b][2], accv[b][3]);
        *reinterpret_cast<float4*>(&hbuf[(size_t)b*HL + gid0]) = o;
    }
}

// ---------------- per-layer parameter precompute ----------------
__global__ __launch_bounds__(256) void k_prep1(const float* __restrict__ ldt,
        const float* __restrict__ Cp, const float* __restrict__ lAr,
        const float* __restrict__ Aimp, int layer,
        float* __restrict__ pdta, float* __restrict__ pwlc, float* __restrict__ pcd2) {
    int t = blockIdx.x*256 + threadIdx.x;   // 8192 = h*32+n
    int h = t >> 5, n = t & 31;
    float dt  = expf(ldt[layer*HH + h]);
    float are = -expf(lAr[(layer*HH + h)*NH + n]);
    float aim = Aimp[(layer*HH + h)*NH + n];
    float dre = are*dt, dimg = aim*dt;
    float er = expf(dre);
    float s, c; sincosf(dimg, &s, &c);
    float wre = er*c, wim = er*s;
    float den = are*are + aim*aim;
    float nre = wre - 1.f, nim = wim;
    float qre = (nre*are + nim*aim)/den;
    float qim = (nim*are - nre*aim)/den;
    float cre = Cp[((layer*HH + h)*NH + n)*2 + 0];
    float cim = Cp[((layer*HH + h)*NH + n)*2 + 1];
    float dcr = cre*qre - cim*qim;
    float dci = cre*qim + cim*qre;
    pcd2[t*2+0] = 2.f*dcr;  pcd2[t*2+1] = 2.f*dci;
    pdta[t*2+0] = dre;      pdta[t*2+1] = dimg;
    float erl = expf(dre*(float)LC);
    float sl, cl; sincosf(dimg*(float)LC, &sl, &cl);
    pwlc[t*2+0] = erl*cl;   pwlc[t*2+1] = erl*sl;
}

// kker[h][m] = Re( sum_n Cd2_n * w_n^m )
__global__ __launch_bounds__(256) void k_kker(const float* __restrict__ pdta,
        const float* __restrict__ pcd2, float* __restrict__ kk) {
    int g = blockIdx.x*256 + threadIdx.x;   // 32768
    int m = g & 127, h = g >> 7;
    float fm = (float)m;
    float acc = 0.f;
    for (int n = 0; n < NH; n++) {
        float dre = pdta[(h*NH+n)*2], dimg = pdta[(h*NH+n)*2+1];
        float er = expf(dre*fm);
        float s, c; sincosf(dimg*fm, &s, &c);
        float dcr = pcd2[(h*NH+n)*2], dci = pcd2[(h*NH+n)*2+1];
        acc += dcr*er*c - dci*er*s;
    }
    kk[g] = acc;
}

// AstB[h][r][m] bf16 : r=2n -> Re(w^(127-m)), r=2n+1 -> Im(w^(127-m))
__global__ __launch_bounds__(256) void k_bldA2(const float* __restrict__ pdta,
                                               unsigned short* __restrict__ AstB) {
    int g = blockIdx.x*256 + threadIdx.x;   // 2,097,152
    int m = g & 127; int r = (g >> 7) & 63; int h = g >> 13;
    int n = r >> 1;
    float e = (float)(127 - m);
    float dre = pdta[(h*NH+n)*2], dimg = pdta[(h*NH+n)*2+1];
    float er = expf(dre*e);
    float s, c; sincosf(dimg*e, &s, &c);
    AstB[g] = f2b((r & 1) ? er*s : er*c);
}

// AcvB[h][j][k] bf16: k<128 -> Toeplitz kker[j-k]; k=128+2n -> Re(w^(j+1)); +1 -> -Im(w^(j+1))
__global__ __launch_bounds__(256) void k_bldC2(const float* __restrict__ pdta,
        const float* __restrict__ kk, unsigned short* __restrict__ AcvB) {
    int g = blockIdx.x*256 + threadIdx.x;   // 6,291,456 = 256*128*192
    int k = g % 192; int j = (g / 192) & 127; int h = g / (192*128);
    float v;
    if (k < 128) {
        v = (j >= k) ? kk[h*128 + (j - k)] : 0.f;
    } else {
        int t = k - 128; int n = t >> 1;
        float dre = pdta[(h*NH+n)*2], dimg = pdta[(h*NH+n)*2+1];
        float e = (float)(j + 1);
        float er = expf(dre*e);
        float s, c; sincosf(dimg*e, &s, &c);
        v = (t & 1) ? (-er*s) : (er*c);
    }
    AcvB[g] = f2b(v);
}

// prepack out_w (all layers) to bf16
__global__ __launch_bounds__(256) void k_prepW(const float* __restrict__ outw,
                                               unsigned short* __restrict__ Wbf) {
    int t = blockIdx.x*256 + threadIdx.x;   // 524288
    Wbf[t] = f2b(outw[t]);
}

// packU: Ubt[h][col][k] = hbuf[b][h][c*128+k], col = b*32+c   (bf16)
__global__ __launch_bounds__(256) void k_packU(const float* __restrict__ hbuf,
                                               unsigned short* __restrict__ Ubt) {
    int t = blockIdx.x*256 + threadIdx.x;   // 4,194,304
    int k8 = t & 15; int col = (t >> 4) & 1023; int h = t >> 14;
    int b = col >> 5, c = col & 31;
    const float* p = &hbuf[(size_t)b*HL + h*LL + c*LC + k8*8];
    float4 v0 = *(const float4*)p;
    float4 v1 = *(const float4*)(p + 4);
    unsigned short* q = &Ubt[(size_t)h*131072 + col*128 + k8*8];
    ushort4 o0 = make_ushort4(f2b(v0.x), f2b(v0.y), f2b(v0.z), f2b(v0.w));
    ushort4 o1 = make_ushort4(f2b(v1.x), f2b(v1.y), f2b(v1.z), f2b(v1.w));
    *(ushort4*)q = o0;
    *(ushort4*)(q + 4) = o1;
}

// ---------------- GEMM-A (MFMA): F[h](64 x 1024) = Ast(64x128) * U(128x1024) ----------------
// FT[h][col][r] f32 (r = 2n/2n+1 interleaved)
__global__ __launch_bounds__(256) void k_gA(const unsigned short* __restrict__ AstB,
        const unsigned short* __restrict__ Ubt, float* __restrict__ FT) {
    int ct = blockIdx.x, h = blockIdx.y;
    int tid = threadIdx.x;
    int w = tid >> 6, l = tid & 63;
    int l16 = l & 15, lk8 = (l >> 4) * 8, e4 = (l >> 4) * 4;
    f4v acc[4][4];
    #pragma unroll
    for (int i = 0; i < 4; i++)
        #pragma unroll
        for (int j = 0; j < 4; j++) acc[i][j] = (f4v){0.f,0.f,0.f,0.f};
    const unsigned short* Ab = AstB + h*8192;
    const unsigned short* Bb = Ubt + (size_t)h*131072 + (size_t)(ct*256 + w*64)*128;
    #pragma unroll
    for (int ks = 0; ks < 4; ks++) {
        int kk = ks*32 + lk8;
        s8v af[4], bfv[4];
        #pragma unroll
        for (int i = 0; i < 4; i++) af[i]  = *(const s8v*)(Ab + (i*16 + l16)*128 + kk);
        #pragma unroll
        for (int j = 0; j < 4; j++) bfv[j] = *(const s8v*)(Bb + (j*16 + l16)*128 + kk);
        #pragma unroll
        for (int i = 0; i < 4; i++)
            #pragma unroll
            for (int j = 0; j < 4; j++)
                acc[i][j] = __builtin_amdgcn_mfma_f32_16x16x32_bf16(af[i], bfv[j], acc[i][j], 0, 0, 0);
    }
    float* Fb = FT + (size_t)h*65536 + (size_t)(ct*256 + w*64)*64;
    #pragma unroll
    for (int i = 0; i < 4; i++)
        #pragma unroll
        for (int j = 0; j < 4; j++)
            *(f4v*)(Fb + (j*16 + l16)*64 + i*16 + e4) = acc[i][j];
}

// ---------------- chunk-prefix scan: FT -> Tbf (bf16) ----------------
__global__ __launch_bounds__(256) void k_scan2(const float* __restrict__ pwlc,
        const float* __restrict__ pcd2, const float* __restrict__ FT,
        unsigned short* __restrict__ Tbf) {
    int t = blockIdx.x*256 + threadIdx.x;   // 262144
    int n = t & 31, b = (t >> 5) & 31, h = t >> 10;
    float wlr = pwlc[(h*NH+n)*2], wli = pwlc[(h*NH+n)*2+1];
    float cr  = pcd2[(h*NH+n)*2], ci  = pcd2[(h*NH+n)*2+1];
    float sr = 0.f, si = 0.f;
    const float* Fp = FT + (size_t)h*65536 + b*2048 + 2*n;
    unsigned short* Tp = Tbf + (size_t)h*65536 + b*2048 + 2*n;
    for (int c = 0; c < NC; c++) {
        float2 f = *(const float2*)(Fp + c*64);
        ushort2 tv = make_ushort2(f2b(cr*sr - ci*si), f2b(cr*si + ci*sr));
        *(ushort2*)(Tp + c*64) = tv;
        float nsr = fmaf(wlr, sr, fmaf(-wli, si, f.x));
        si = fmaf(wlr, si, fmaf(wli, sr, f.y));
        sr = nsr;
    }
}

// ---------------- GEMM-B (MFMA): y[h](128 x 1024) = Acv(128x192)*[U;T], fused skip+GELU, out bf16 ----------------
__global__ __launch_bounds__(256) void k_gB(const unsigned short* __restrict__ AcvB,
        const unsigned short* __restrict__ Ubt, const unsigned short* __restrict__ Tbf,
        const float* __restrict__ hbuf, const float* __restrict__ Dsk, int layer,
        unsigned short* __restrict__ Ybf) {
    int ct = blockIdx.x, h = blockIdx.y;
    int tid = threadIdx.x;
    int w = tid >> 6, l = tid & 63;
    int l16 = l & 15, lk8 = (l >> 4) * 8, e4 = (l >> 4) * 4;
    int wm = (w >> 1) * 64, wn = (w & 1) * 64;
    int colb = ct*128 + wn;
    f4v acc[4][4];
    #pragma unroll
    for (int i = 0; i < 4; i++)
        #pragma unroll
        for (int j = 0; j < 4; j++) acc[i][j] = (f4v){0.f,0.f,0.f,0.f};
    const unsigned short* Ab = AcvB + (size_t)h*24576;
    #pragma unroll
    for (int ks = 0; ks < 4; ks++) {          // K rows 0..127 from U
        int kk = ks*32 + lk8;
        s8v af[4], bfv[4];
        #pragma unroll
        for (int i = 0; i < 4; i++) af[i] = *(const s8v*)(Ab + (wm + i*16 + l16)*192 + kk);
        #pragma unroll
        for (int j = 0; j < 4; j++)
            bfv[j] = *(const s8v*)(Ubt + (size_t)h*131072 + (colb + j*16 + l16)*128 + kk);
        #pragma unroll
        for (int i = 0; i < 4; i++)
            #pragma unroll
            for (int j = 0; j < 4; j++)
                acc[i][j] = __builtin_amdgcn_mfma_f32_16x16x32_bf16(af[i], bfv[j], acc[i][j], 0, 0, 0);
    }
    #pragma unroll
    for (int ks = 0; ks < 2; ks++) {          // K rows 128..191 from T
        int kk = ks*32 + lk8;
        s8v af[4], bfv[4];
        #pragma unroll
        for (int i = 0; i < 4; i++) af[i] = *(const s8v*)(Ab + (wm + i*16 + l16)*192 + 128 + kk);
        #pragma unroll
        for (int j = 0; j < 4; j++)
            bfv[j] = *(const s8v*)(Tbf + (size_t)h*65536 + (colb + j*16 + l16)*64 + kk);
        #pragma unroll
        for (int i = 0; i < 4; i++)
            #pragma unroll
            for (int j = 0; j < 4; j++)
                acc[i][j] = __builtin_amdgcn_mfma_f32_16x16x32_bf16(af[i], bfv[j], acc[i][j], 0, 0, 0);
    }
    float dsk = Dsk[layer*HH + h];
    #pragma unroll
    for (int i = 0; i < 4; i++) {
        int m0 = wm + i*16 + e4;
        #pragma unroll
        for (int j = 0; j < 4; j++) {
            int col = colb + j*16 + l16;
            int b = col >> 5, c = col & 31;
            float4 u = *(const float4*)&hbuf[(size_t)b*HL + h*LL + c*LC + m0];
            float uu[4] = {u.x, u.y, u.z, u.w};
            unsigned short ov[4];
            #pragma unroll
            for (int e = 0; e < 4; e++) {
                float yv = acc[i][j][e] + dsk*uu[e];
                ov[e] = f2b(0.5f*yv*(1.f + erff(yv*0.70710678118f)));
            }
            *(ushort4*)&Ybf[(size_t)h*BLn + col*128 + m0] = make_ushort4(ov[0], ov[1], ov[2], ov[3]);
        }
    }
}

// ---------------- packY: Ybt[n][hch] = Ybf[hch][n] (64x64 LDS tile transpose) ----------------
__global__ __launch_bounds__(256) void k_packY(const unsigned short* __restrict__ Ybf,
                                               unsigned short* __restrict__ Ybt) {
    __shared__ unsigned short t[64][72];
    int n0 = (blockIdx.x >> 2) * 64;
    int h0 = (blockIdx.x & 3) * 64;
    int tid = threadIdx.x;
    int jn = (tid & 15) * 4, hr = tid >> 4;
    #pragma unroll
    for (int it = 0; it < 4; it++) {
        int hh = hr + it*16;
        ushort4 v = *(const ushort4*)&Ybf[(size_t)(h0+hh)*BLn + n0 + jn];
        t[jn+0][hh] = v.x; t[jn+1][hh] = v.y; t[jn+2][hh] = v.z; t[jn+3][hh] = v.w;
    }
    __syncthreads();
    int jh = (tid & 15) * 4, nr = tid >> 4;
    #pragma unroll
    for (int it = 0; it < 4; it++) {
        int nn = nr + it*16;
        ushort4 v = make_ushort4(t[nn][jh], t[nn][jh+1], t[nn][jh+2], t[nn][jh+3]);
        *(ushort4*)&Ybt[(size_t)(n0+nn)*HH + h0 + jh] = v;
    }
}

// ---------------- GEMM-C (MFMA): z(512 x 131072) = W*Y, fused bias+GLU+residual ----------------
__global__ __launch_bounds__(512) void k_gC(const unsigned short* __restrict__ Wb,
        const float* __restrict__ outb, const unsigned short* __restrict__ Ybt,
        float* __restrict__ hbuf) {
    int nt = blockIdx.x;
    int n0 = nt*64;
    int tid = threadIdx.x;
    int w = tid >> 6, l = tid & 63;
    int l16 = l & 15, lk8 = (l >> 4) * 8, e4 = (l >> 4) * 4;
    int ra = w*32 + l16;
    f4v acc[4][4];
    #pragma unroll
    for (int i = 0; i < 4; i++)
        #pragma unroll
        for (int j = 0; j < 4; j++) acc[i][j] = (f4v){0.f,0.f,0.f,0.f};
    const unsigned short* W0 = Wb + ra*HH;
    const unsigned short* W1 = Wb + (ra+16)*HH;
    const unsigned short* W2 = Wb + (ra+256)*HH;
    const unsigned short* W3 = Wb + (ra+272)*HH;
    #pragma unroll
    for (int ks = 0; ks < 8; ks++) {
        int kk = ks*32 + lk8;
        s8v a0 = *(const s8v*)(W0 + kk);
        s8v a1 = *(const s8v*)(W1 + kk);
        s8v a2 = *(const s8v*)(W2 + kk);
        s8v a3 = *(const s8v*)(W3 + kk);
        s8v bfv[4];
        #pragma unroll
        for (int j = 0; j < 4; j++)
            bfv[j] = *(const s8v*)(Ybt + (size_t)(n0 + j*16 + l16)*HH + kk);
        #pragma unroll
        for (int j = 0; j < 4; j++) {
            acc[0][j] = __builtin_amdgcn_mfma_f32_16x16x32_bf16(a0, bfv[j], acc[0][j], 0, 0, 0);
            acc[1][j] = __builtin_amdgcn_mfma_f32_16x16x32_bf16(a1, bfv[j], acc[1][j], 0, 0, 0);
            acc[2][j] = __builtin_amdgcn_mfma_f32_16x16x32_bf16(a2, bfv[j], acc[2][j], 0, 0, 0);
            acc[3][j] = __builtin_amdgcn_mfma_f32_16x16x32_bf16(a3, bfv[j], acc[3][j], 0, 0, 0);
        }
    }
    int col = nt >> 1;
    int b = col >> 5, c = col & 31;
    int lp0 = (nt & 1) * 64;
    #pragma unroll
    for (int i = 0; i < 2; i++) {
        int ob = w*32 + i*16 + e4;
        #pragma unroll
        for (int e = 0; e < 4; e++) {
            int o = ob + e;
            float ba  = outb[o];
            float bb2 = outb[o + 256];
            #pragma unroll
            for (int j = 0; j < 4; j++) {
                float za = acc[i][j][e] + ba;
                float zb = acc[i+2][j][e] + bb2;
                float sig = 1.f/(1.f + expf(-zb));
                float* hp = &hbuf[(size_t)b*HL + o*LL + c*LC + lp0 + j*16 + l16];
                *hp = *hp + za*sig;
            }
        }
    }
}

// ---------------- decoder ----------------
__global__ __launch_bounds__(256) void k_dec(const float* __restrict__ hbuf,
        const float* __restrict__ dw, const float* __restrict__ db,
        float* __restrict__ out) {
    __shared__ float wsm[HH];
    int tid = threadIdx.x;
    wsm[tid] = dw[tid];
    __syncthreads();
    int g = (blockIdx.x*256 + tid)*4;
    int b = g >> 12, lp = g & 4095;
    float a0 = db[0], a1 = a0, a2 = a0, a3 = a0;
    for (int hh = 0; hh < HH; hh++) {
        float wv = wsm[hh];
        float4 hv = *(const float4*)&hbuf[(size_t)b*HL + hh*LL + lp];
        a0 = fmaf(wv, hv.x, a0);
        a1 = fmaf(wv, hv.y, a1);
        a2 = fmaf(wv, hv.z, a2);
        a3 = fmaf(wv, hv.w, a3);
    }
    *(float4*)&out[g] = make_float4(a0, a1, a2, a3);
}

extern "C" void kernel_launch(void* const* d_in, const int* in_sizes, int n_in,
                              void* d_out, int out_size, void* d_ws, size_t ws_size,
                              hipStream_t stream) {
    (void)in_sizes; (void)n_in; (void)out_size; (void)ws_size;
    const float* x    = (const float*)d_in[0];
    const float* ew   = (const float*)d_in[1];
    const float* ldt  = (const float*)d_in[2];
    const float* Cp   = (const float*)d_in[3];
    const float* lAr  = (const float*)d_in[4];
    const float* Aimp = (const float*)d_in[5];
    const float* Dsk  = (const float*)d_in[6];
    const float* outw = (const float*)d_in[7];
    const float* outb = (const float*)d_in[8];
    const float* dw   = (const float*)d_in[9];
    const float* db   = (const float*)d_in[10];

    float* ws = (float*)d_ws;
    float* hbuf = ws;                                   // 33,554,432 f32
    float* FT   = ws + 33554432UL;                      // 16,777,216 f32  (aliased: Ybf bf16 after scan)
    unsigned short* Ybf = (unsigned short*)FT;
    unsigned short* Ubt = (unsigned short*)(ws + 50331648UL);   // 33,554,432 bf16 (aliased: Ybt after gB)
    unsigned short* Ybt = Ubt;
    unsigned short* Tbf = (unsigned short*)(ws + 67108864UL);   // 16,777,216 bf16
    unsigned short* AstB= (unsigned short*)(ws + 75497472UL);   //  2,097,152 bf16
    unsigned short* AcvB= (unsigned short*)(ws + 76546048UL);   //  6,291,456 bf16
    unsigned short* Wbf = (unsigned short*)(ws + 79691776UL);   //    524,288 bf16
    float* kk   = ws + 79953920UL;
    float* pdta = ws + 79986688UL;
    float* pwlc = ws + 80003072UL;
    float* pcd2 = ws + 80019456UL;      // end ~320.1 MB

    k_prepW<<<2048, 256, 0, stream>>>(outw, Wbf);
    k_enc<<<1024, 256, 0, stream>>>(x, ew, hbuf);
    for (int layer = 0; layer < NLAY; layer++) {
        k_prep1<<<32, 256, 0, stream>>>(ldt, Cp, lAr, Aimp, layer, pdta, pwlc, pcd2);
        k_kker<<<128, 256, 0, stream>>>(pdta, pcd2, kk);
        k_bldA2<<<8192, 256, 0, stream>>>(pdta, AstB);
        k_bldC2<<<24576, 256, 0, stream>>>(pdta, kk, AcvB);
        k_packU<<<16384, 256, 0, stream>>>(hbuf, Ubt);
        k_gA<<<dim3(4, 256), 256, 0, stream>>>(AstB, Ubt, FT);
        k_scan2<<<1024, 256, 0, stream>>>(pwlc, pcd2, FT, Tbf);
        k_gB<<<dim3(8, 256), 256, 0, stream>>>(AcvB, Ubt, Tbf, hbuf, Dsk, layer, Ybf);
        k_packY<<<8192, 256, 0, stream>>>(Ybf, Ybt);
        k_gC<<<2048, 512, 0, stream>>>(Wbf + layer*131072, outb + layer*512, Ybt, hbuf);
    }
    k_dec<<<128, 256, 0, stream>>>(hbuf, dw, db, (float*)d_out);
}

// Round 3
// 1613.109 us; speedup vs baseline: 2.1406x; 1.2038x over previous
//
#include <hip/hip_runtime.h>
#include <hip/hip_bf16.h>
#include <math.h>

#define BB   32
#define DIN  100
#define HH   256
#define NLAY 4
#define NH   32
#define LL   4096
#define LC   128
#define NC   32
#define HL   (HH*LL)   // 1048576
#define BLn  (BB*LL)   // 131072

typedef __attribute__((ext_vector_type(8))) short s8v;
typedef __attribute__((ext_vector_type(4))) float f4v;

__device__ inline unsigned short f2b(float x) {
    unsigned int u = __float_as_uint(x);
    unsigned int r = (u + 0x7fffu + ((u >> 16) & 1u)) >> 16;
    return (unsigned short)r;
}
__device__ inline float b2f(unsigned short u) {
    return __uint_as_float(((unsigned int)u) << 16);
}
__device__ inline s8v pack8(float4 a, float4 b) {
    union { s8v v; __hip_bfloat162 h[4]; } r;
    r.h[0] = __float22bfloat162_rn(make_float2(a.x, a.y));
    r.h[1] = __float22bfloat162_rn(make_float2(a.z, a.w));
    r.h[2] = __float22bfloat162_rn(make_float2(b.x, b.y));
    r.h[3] = __float22bfloat162_rn(make_float2(b.z, b.w));
    return r.v;
}

// ---------------- encoder ----------------
__global__ __launch_bounds__(256) void k_enc(const float* __restrict__ x,
                                             const float* __restrict__ ew,
                                             float* __restrict__ hbuf) {
    __shared__ __align__(16) float xs[DIN*BB];
    int tid = threadIdx.x;
    for (int idx = tid; idx < DIN*BB; idx += 256) {
        int b = idx & 31, i = idx >> 5;
        xs[i*BB + b] = x[b*DIN + i];
    }
    __syncthreads();
    int gid0 = (blockIdx.x*256 + tid) * 4;
    float accv[BB][4];
    #pragma unroll
    for (int b = 0; b < BB; b++) { accv[b][0]=0.f; accv[b][1]=0.f; accv[b][2]=0.f; accv[b][3]=0.f; }
    for (int i = 0; i < DIN; i++) {
        float4 wv = *reinterpret_cast<const float4*>(&ew[(size_t)i*HL + gid0]);
        float wvv[4] = {wv.x, wv.y, wv.z, wv.w};
        #pragma unroll
        for (int b4 = 0; b4 < 8; b4++) {
            float4 xv = *reinterpret_cast<const float4*>(&xs[i*BB + b4*4]);
            float xc[4] = {xv.x, xv.y, xv.z, xv.w};
            #pragma unroll
            for (int q = 0; q < 4; q++) {
                int b = b4*4 + q;
                accv[b][0] = fmaf(xc[q], wvv[0], accv[b][0]);
                accv[b][1] = fmaf(xc[q], wvv[1], accv[b][1]);
                accv[b][2] = fmaf(xc[q], wvv[2], accv[b][2]);
                accv[b][3] = fmaf(xc[q], wvv[3], accv[b][3]);
            }
        }
    }
    #pragma unroll
    for (int b = 0; b < BB; b++) {
        float4 o = make_float4(accv[b][0], accv[b][1], accv[b][2], accv[b][3]);
        *reinterpret_cast<float4*>(&hbuf[(size_t)b*HL + gid0]) = o;
    }
}

// ---------------- per-layer parameter precompute ----------------
__global__ __launch_bounds__(256) void k_prep1(const float* __restrict__ ldt,
        const float* __restrict__ Cp, const float* __restrict__ lAr,
        const float* __restrict__ Aimp, int layer,
        float* __restrict__ pdta, float* __restrict__ pwlc, float* __restrict__ pcd2) {
    int t = blockIdx.x*256 + threadIdx.x;   // 8192 = h*32+n
    int h = t >> 5, n = t & 31;
    float dt  = expf(ldt[layer*HH + h]);
    float are = -expf(lAr[(layer*HH + h)*NH + n]);
    float aim = Aimp[(layer*HH + h)*NH + n];
    float dre = are*dt, dimg = aim*dt;
    float er = expf(dre);
    float s, c; sincosf(dimg, &s, &c);
    float wre = er*c, wim = er*s;
    float den = are*are + aim*aim;
    float nre = wre - 1.f, nim = wim;
    float qre = (nre*are + nim*aim)/den;
    float qim = (nim*are - nre*aim)/den;
    float cre = Cp[((layer*HH + h)*NH + n)*2 + 0];
    float cim = Cp[((layer*HH + h)*NH + n)*2 + 1];
    float dcr = cre*qre - cim*qim;
    float dci = cre*qim + cim*qre;
    pcd2[t*2+0] = 2.f*dcr;  pcd2[t*2+1] = 2.f*dci;
    pdta[t*2+0] = dre;      pdta[t*2+1] = dimg;
    float erl = expf(dre*(float)LC);
    float sl, cl; sincosf(dimg*(float)LC, &sl, &cl);
    pwlc[t*2+0] = erl*cl;   pwlc[t*2+1] = erl*sl;
}

// kker[h][m] = Re( sum_n Cd2_n * w_n^m )
__global__ __launch_bounds__(256) void k_kker(const float* __restrict__ pdta,
        const float* __restrict__ pcd2, float* __restrict__ kk) {
    int g = blockIdx.x*256 + threadIdx.x;   // 32768
    int m = g & 127, h = g >> 7;
    float fm = (float)m;
    float acc = 0.f;
    for (int n = 0; n < NH; n++) {
        float dre = pdta[(h*NH+n)*2], dimg = pdta[(h*NH+n)*2+1];
        float er = expf(dre*fm);
        float s, c; sincosf(dimg*fm, &s, &c);
        float dcr = pcd2[(h*NH+n)*2], dci = pcd2[(h*NH+n)*2+1];
        acc += dcr*er*c - dci*er*s;
    }
    kk[g] = acc;
}

// AstB[h][r][m] bf16 : r=2n -> Re(w^(127-m)), r=2n+1 -> Im(w^(127-m))
__global__ __launch_bounds__(256) void k_bldA2(const float* __restrict__ pdta,
                                               unsigned short* __restrict__ AstB) {
    int g = blockIdx.x*256 + threadIdx.x;   // 2,097,152
    int m = g & 127; int r = (g >> 7) & 63; int h = g >> 13;
    int n = r >> 1;
    float e = (float)(127 - m);
    float dre = pdta[(h*NH+n)*2], dimg = pdta[(h*NH+n)*2+1];
    float er = expf(dre*e);
    float s, c; sincosf(dimg*e, &s, &c);
    AstB[g] = f2b((r & 1) ? er*s : er*c);
}

// AcvB[h][j][k] bf16: k<128 -> Toeplitz kker[j-k]; k=128+2n -> Re(w^(j+1)); +1 -> -Im(w^(j+1))
__global__ __launch_bounds__(256) void k_bldC2(const float* __restrict__ pdta,
        const float* __restrict__ kk, unsigned short* __restrict__ AcvB) {
    int g = blockIdx.x*256 + threadIdx.x;   // 6,291,456 = 256*128*192
    int k = g % 192; int j = (g / 192) & 127; int h = g / (192*128);
    float v;
    if (k < 128) {
        v = (j >= k) ? kk[h*128 + (j - k)] : 0.f;
    } else {
        int t = k - 128; int n = t >> 1;
        float dre = pdta[(h*NH+n)*2], dimg = pdta[(h*NH+n)*2+1];
        float e = (float)(j + 1);
        float er = expf(dre*e);
        float s, c; sincosf(dimg*e, &s, &c);
        v = (t & 1) ? (-er*s) : (er*c);
    }
    AcvB[g] = f2b(v);
}

// prepack out_w (all layers) to bf16
__global__ __launch_bounds__(256) void k_prepW(const float* __restrict__ outw,
                                               unsigned short* __restrict__ Wbf) {
    int t = blockIdx.x*256 + threadIdx.x;   // 524288
    Wbf[t] = f2b(outw[t]);
}

// ---------------- fused S4D core: gA + chunk-scan + gB per (h, 8-batch group) ----------------
// grid (4, 256): ct (256 cols = 8 b x 32 c), h. 256 threads.
__global__ __launch_bounds__(256) void k_BG(const unsigned short* __restrict__ AstB,
        const unsigned short* __restrict__ AcvB, const float* __restrict__ hbuf,
        const float* __restrict__ pwlc, const float* __restrict__ pcd2,
        const float* __restrict__ DskL, unsigned short* __restrict__ Ybf) {
    __shared__ unsigned short Fl[256*64];   // 32 KB, XOR-swizzled [lcol][r]
    int ct = blockIdx.x, h = blockIdx.y;
    int tid = threadIdx.x;
    int w = tid >> 6, l = tid & 63;
    int l16 = l & 15, lk8 = (l >> 4)*8, e4 = (l >> 4)*4;
    int lcol0 = w*64;

    // per-j column bases (global u pointers)
    int lcolj[4]; const float* up[4];
    #pragma unroll
    for (int j = 0; j < 4; j++) {
        lcolj[j] = lcol0 + j*16 + l16;
        int gcol = ct*256 + lcolj[j];
        int b = gcol >> 5, c = gcol & 31;
        up[j] = hbuf + (size_t)b*HL + (size_t)h*LL + c*LC;
    }

    // ---- phase A: F(64 x 256) = Ast(64x128) * U ----
    {
        f4v acc[4][4];
        #pragma unroll
        for (int i = 0; i < 4; i++)
            #pragma unroll
            for (int j = 0; j < 4; j++) acc[i][j] = (f4v){0.f,0.f,0.f,0.f};
        const unsigned short* Ab = AstB + h*8192;
        #pragma unroll
        for (int ks = 0; ks < 4; ks++) {
            int kk = ks*32 + lk8;
            s8v af[4], bfv[4];
            #pragma unroll
            for (int i = 0; i < 4; i++) af[i] = *(const s8v*)(Ab + (i*16 + l16)*128 + kk);
            #pragma unroll
            for (int j = 0; j < 4; j++) {
                float4 u0 = *(const float4*)(up[j] + kk);
                float4 u1 = *(const float4*)(up[j] + kk + 4);
                bfv[j] = pack8(u0, u1);
            }
            #pragma unroll
            for (int i = 0; i < 4; i++)
                #pragma unroll
                for (int j = 0; j < 4; j++)
                    acc[i][j] = __builtin_amdgcn_mfma_f32_16x16x32_bf16(af[i], bfv[j], acc[i][j], 0, 0, 0);
        }
        // store F to LDS (bf16, swizzled)
        #pragma unroll
        for (int i = 0; i < 4; i++)
            #pragma unroll
            for (int j = 0; j < 4; j++) {
                int lcol = lcolj[j];
                int idx = (lcol*64 + i*16 + e4) ^ ((lcol & 7) << 3);
                ushort4 fv = make_ushort4(f2b(acc[i][j][0]), f2b(acc[i][j][1]),
                                          f2b(acc[i][j][2]), f2b(acc[i][j][3]));
                *(ushort4*)&Fl[idx] = fv;
            }
    }
    __syncthreads();

    // ---- chunk-prefix scan (in place: F -> T) ----
    {
        int n = tid & 31, bl = tid >> 5;
        int hn2 = (h*NH + n)*2;
        float wlr = pwlc[hn2], wli = pwlc[hn2+1];
        float cr  = pcd2[hn2], ci  = pcd2[hn2+1];
        float sr = 0.f, si = 0.f;
        #pragma unroll 4
        for (int c = 0; c < NC; c++) {
            int lcol = bl*32 + c;
            int idx = (lcol*64 + 2*n) ^ ((lcol & 7) << 3);
            ushort2 fv = *(ushort2*)&Fl[idx];
            float fr = b2f(fv.x), fi = b2f(fv.y);
            *(ushort2*)&Fl[idx] = make_ushort2(f2b(cr*sr - ci*si), f2b(cr*si + ci*sr));
            float nsr = fmaf(wlr, sr, fmaf(-wli, si, fr));
            si = fmaf(wlr, si, fmaf(wli, sr, fi));
            sr = nsr;
        }
    }
    __syncthreads();

    // ---- phase B: y(128 x 256) = Acv(128x192) * [U; T], skip + GELU, write bf16 ----
    float dsk = DskL[h];
    const unsigned short* Cb = AcvB + (size_t)h*24576;
    #pragma unroll
    for (int mh = 0; mh < 2; mh++) {
        f4v acc[4][4];
        #pragma unroll
        for (int i = 0; i < 4; i++)
            #pragma unroll
            for (int j = 0; j < 4; j++) acc[i][j] = (f4v){0.f,0.f,0.f,0.f};
        #pragma unroll
        for (int ks = 0; ks < 4; ks++) {        // K 0..127 from U (f32 global -> bf16)
            int kk = ks*32 + lk8;
            s8v af[4], bfv[4];
            #pragma unroll
            for (int i = 0; i < 4; i++)
                af[i] = *(const s8v*)(Cb + (mh*64 + i*16 + l16)*192 + kk);
            #pragma unroll
            for (int j = 0; j < 4; j++) {
                float4 u0 = *(const float4*)(up[j] + kk);
                float4 u1 = *(const float4*)(up[j] + kk + 4);
                bfv[j] = pack8(u0, u1);
            }
            #pragma unroll
            for (int i = 0; i < 4; i++)
                #pragma unroll
                for (int j = 0; j < 4; j++)
                    acc[i][j] = __builtin_amdgcn_mfma_f32_16x16x32_bf16(af[i], bfv[j], acc[i][j], 0, 0, 0);
        }
        #pragma unroll
        for (int ks = 0; ks < 2; ks++) {        // K 128..191 from T (LDS)
            int kk2 = ks*32 + lk8;
            s8v af[4], bfv[4];
            #pragma unroll
            for (int i = 0; i < 4; i++)
                af[i] = *(const s8v*)(Cb + (mh*64 + i*16 + l16)*192 + 128 + kk2);
            #pragma unroll
            for (int j = 0; j < 4; j++) {
                int lcol = lcolj[j];
                int idx = (lcol*64 + kk2) ^ ((lcol & 7) << 3);
                bfv[j] = *(const s8v*)&Fl[idx];
            }
            #pragma unroll
            for (int i = 0; i < 4; i++)
                #pragma unroll
                for (int j = 0; j < 4; j++)
                    acc[i][j] = __builtin_amdgcn_mfma_f32_16x16x32_bf16(af[i], bfv[j], acc[i][j], 0, 0, 0);
        }
        // epilogue: skip (f32 u) + exact GELU -> Ybf
        #pragma unroll
        for (int i = 0; i < 4; i++) {
            int m0 = mh*64 + i*16 + e4;
            #pragma unroll
            for (int j = 0; j < 4; j++) {
                float4 u = *(const float4*)(up[j] + m0);
                float uu[4] = {u.x, u.y, u.z, u.w};
                unsigned short ov[4];
                #pragma unroll
                for (int e = 0; e < 4; e++) {
                    float yv = acc[i][j][e] + dsk*uu[e];
                    ov[e] = f2b(0.5f*yv*(1.f + erff(yv*0.70710678118f)));
                }
                int gcol = ct*256 + lcolj[j];
                *(ushort4*)&Ybf[(size_t)h*BLn + (size_t)gcol*LC + m0] =
                    make_ushort4(ov[0], ov[1], ov[2], ov[3]);
            }
        }
    }
}

// ---------------- packY: Ybt[n][h] = Ybf[h][n] ----------------
__global__ __launch_bounds__(256) void k_packY(const unsigned short* __restrict__ Ybf,
                                               unsigned short* __restrict__ Ybt) {
    __shared__ unsigned short t[64][72];
    int n0 = (blockIdx.x >> 2) * 64;
    int h0 = (blockIdx.x & 3) * 64;
    int tid = threadIdx.x;
    int jn = (tid & 15) * 4, hr = tid >> 4;
    #pragma unroll
    for (int it = 0; it < 4; it++) {
        int hh = hr + it*16;
        ushort4 v = *(const ushort4*)&Ybf[(size_t)(h0+hh)*BLn + n0 + jn];
        t[jn+0][hh] = v.x; t[jn+1][hh] = v.y; t[jn+2][hh] = v.z; t[jn+3][hh] = v.w;
    }
    __syncthreads();
    int jh = (tid & 15) * 4, nr = tid >> 4;
    #pragma unroll
    for (int it = 0; it < 4; it++) {
        int nn = nr + it*16;
        ushort4 v = make_ushort4(t[nn][jh], t[nn][jh+1], t[nn][jh+2], t[nn][jh+3]);
        *(ushort4*)&Ybt[(size_t)(n0+nn)*HH + h0 + jh] = v;
    }
}

// ---------------- GEMM-C (MFMA): z(512 x 131072) = W*Y, fused bias+GLU+residual ----------------
__global__ __launch_bounds__(512) void k_gC(const unsigned short* __restrict__ Wb,
        const float* __restrict__ outb, const unsigned short* __restrict__ Ybt,
        float* __restrict__ hbuf) {
    int nt = blockIdx.x;
    int n0 = nt*64;
    int tid = threadIdx.x;
    int w = tid >> 6, l = tid & 63;
    int l16 = l & 15, lk8 = (l >> 4) * 8, e4 = (l >> 4) * 4;
    int ra = w*32 + l16;
    f4v acc[4][4];
    #pragma unroll
    for (int i = 0; i < 4; i++)
        #pragma unroll
        for (int j = 0; j < 4; j++) acc[i][j] = (f4v){0.f,0.f,0.f,0.f};
    const unsigned short* W0 = Wb + ra*HH;
    const unsigned short* W1 = Wb + (ra+16)*HH;
    const unsigned short* W2 = Wb + (ra+256)*HH;
    const unsigned short* W3 = Wb + (ra+272)*HH;
    #pragma unroll
    for (int ks = 0; ks < 8; ks++) {
        int kk = ks*32 + lk8;
        s8v a0 = *(const s8v*)(W0 + kk);
        s8v a1 = *(const s8v*)(W1 + kk);
        s8v a2 = *(const s8v*)(W2 + kk);
        s8v a3 = *(const s8v*)(W3 + kk);
        s8v bfv[4];
        #pragma unroll
        for (int j = 0; j < 4; j++)
            bfv[j] = *(const s8v*)(Ybt + (size_t)(n0 + j*16 + l16)*HH + kk);
        #pragma unroll
        for (int j = 0; j < 4; j++) {
            acc[0][j] = __builtin_amdgcn_mfma_f32_16x16x32_bf16(a0, bfv[j], acc[0][j], 0, 0, 0);
            acc[1][j] = __builtin_amdgcn_mfma_f32_16x16x32_bf16(a1, bfv[j], acc[1][j], 0, 0, 0);
            acc[2][j] = __builtin_amdgcn_mfma_f32_16x16x32_bf16(a2, bfv[j], acc[2][j], 0, 0, 0);
            acc[3][j] = __builtin_amdgcn_mfma_f32_16x16x32_bf16(a3, bfv[j], acc[3][j], 0, 0, 0);
        }
    }
    int col = nt >> 1;
    int b = col >> 5, c = col & 31;
    int lp0 = (nt & 1) * 64;
    #pragma unroll
    for (int i = 0; i < 2; i++) {
        int ob = w*32 + i*16 + e4;
        #pragma unroll
        for (int e = 0; e < 4; e++) {
            int o = ob + e;
            float ba  = outb[o];
            float bb2 = outb[o + 256];
            #pragma unroll
            for (int j = 0; j < 4; j++) {
                float za = acc[i][j][e] + ba;
                float zb = acc[i+2][j][e] + bb2;
                float sig = 1.f/(1.f + expf(-zb));
                float* hp = &hbuf[(size_t)b*HL + o*LL + c*LC + lp0 + j*16 + l16];
                *hp = *hp + za*sig;
            }
        }
    }
}

// ---------------- decoder ----------------
__global__ __launch_bounds__(256) void k_dec(const float* __restrict__ hbuf,
        const float* __restrict__ dw, const float* __restrict__ db,
        float* __restrict__ out) {
    __shared__ float wsm[HH];
    int tid = threadIdx.x;
    wsm[tid] = dw[tid];
    __syncthreads();
    int g = (blockIdx.x*256 + tid)*4;
    int b = g >> 12, lp = g & 4095;
    float a0 = db[0], a1 = a0, a2 = a0, a3 = a0;
    for (int hh = 0; hh < HH; hh++) {
        float wv = wsm[hh];
        float4 hv = *(const float4*)&hbuf[(size_t)b*HL + hh*LL + lp];
        a0 = fmaf(wv, hv.x, a0);
        a1 = fmaf(wv, hv.y, a1);
        a2 = fmaf(wv, hv.z, a2);
        a3 = fmaf(wv, hv.w, a3);
    }
    *(float4*)&out[g] = make_float4(a0, a1, a2, a3);
}

extern "C" void kernel_launch(void* const* d_in, const int* in_sizes, int n_in,
                              void* d_out, int out_size, void* d_ws, size_t ws_size,
                              hipStream_t stream) {
    (void)in_sizes; (void)n_in; (void)out_size; (void)ws_size;
    const float* x    = (const float*)d_in[0];
    const float* ew   = (const float*)d_in[1];
    const float* ldt  = (const float*)d_in[2];
    const float* Cp   = (const float*)d_in[3];
    const float* lAr  = (const float*)d_in[4];
    const float* Aimp = (const float*)d_in[5];
    const float* Dsk  = (const float*)d_in[6];
    const float* outw = (const float*)d_in[7];
    const float* outb = (const float*)d_in[8];
    const float* dw   = (const float*)d_in[9];
    const float* db   = (const float*)d_in[10];

    float* ws = (float*)d_ws;
    float* hbuf = ws;                                           // 33,554,432 f32
    unsigned short* Ybf = (unsigned short*)(ws + 33554432UL);   // 33,554,432 bf16
    unsigned short* Ybt = (unsigned short*)(ws + 50331648UL);   // 33,554,432 bf16
    unsigned short* AstB= (unsigned short*)(ws + 67108864UL);   //  2,097,152 bf16
    unsigned short* AcvB= (unsigned short*)(ws + 68157440UL);   //  6,291,456 bf16
    unsigned short* Wbf = (unsigned short*)(ws + 71303168UL);   //    524,288 bf16
    float* kk   = ws + 71565312UL;
    float* pdta = ws + 71598080UL;
    float* pwlc = ws + 71614464UL;
    float* pcd2 = ws + 71630848UL;      // end ~286.6 MB

    k_prepW<<<2048, 256, 0, stream>>>(outw, Wbf);
    k_enc<<<1024, 256, 0, stream>>>(x, ew, hbuf);
    for (int layer = 0; layer < NLAY; layer++) {
        k_prep1<<<32, 256, 0, stream>>>(ldt, Cp, lAr, Aimp, layer, pdta, pwlc, pcd2);
        k_kker<<<128, 256, 0, stream>>>(pdta, pcd2, kk);
        k_bldA2<<<8192, 256, 0, stream>>>(pdta, AstB);
        k_bldC2<<<24576, 256, 0, stream>>>(pdta, kk, AcvB);
        k_BG<<<dim3(4, 256), 256, 0, stream>>>(AstB, AcvB, hbuf, pwlc, pcd2,
                                               Dsk + layer*HH, Ybf);
        k_packY<<<8192, 256, 0, stream>>>(Ybf, Ybt);
        k_gC<<<2048, 512, 0, stream>>>(Wbf + layer*131072, outb + layer*512, Ybt, hbuf);
    }
    k_dec<<<128, 256, 0, stream>>>(hbuf, dw, db, (float*)d_out);
}

// Round 4
// 1506.910 us; speedup vs baseline: 2.2915x; 1.0705x over previous
//
#include <hip/hip_runtime.h>
#include <hip/hip_bf16.h>
#include <math.h>

#define BB   32
#define DIN  100
#define HH   256
#define NLAY 4
#define NH   32
#define LL   4096
#define LC   128
#define NC   32
#define HL   (HH*LL)   // 1048576
#define BLn  (BB*LL)   // 131072

typedef __attribute__((ext_vector_type(8))) short s8v;
typedef __attribute__((ext_vector_type(4))) float f4v;

__device__ inline unsigned short f2b(float x) {
    unsigned int u = __float_as_uint(x);
    unsigned int r = (u + 0x7fffu + ((u >> 16) & 1u)) >> 16;
    return (unsigned short)r;
}
__device__ inline float b2f(unsigned short u) {
    return __uint_as_float(((unsigned int)u) << 16);
}

// ---------------- encoder: hb[h][b][l] bf16 = sum_i x[b][i]*ew[i][h][l] ----------------
__global__ __launch_bounds__(256) void k_enc(const float* __restrict__ x,
                                             const float* __restrict__ ew,
                                             unsigned short* __restrict__ hb) {
    __shared__ __align__(16) float xs[DIN*BB];
    int tid = threadIdx.x;
    for (int idx = tid; idx < DIN*BB; idx += 256) {
        int b = idx & 31, i = idx >> 5;
        xs[i*BB + b] = x[b*DIN + i];
    }
    __syncthreads();
    int gid0 = (blockIdx.x*256 + tid) * 4;   // (h,hw) flattened
    int h = gid0 >> 12, hw0 = gid0 & 4095;
    float accv[BB][4];
    #pragma unroll
    for (int b = 0; b < BB; b++) { accv[b][0]=0.f; accv[b][1]=0.f; accv[b][2]=0.f; accv[b][3]=0.f; }
    for (int i = 0; i < DIN; i++) {
        float4 wv = *reinterpret_cast<const float4*>(&ew[(size_t)i*HL + gid0]);
        float wvv[4] = {wv.x, wv.y, wv.z, wv.w};
        #pragma unroll
        for (int b4 = 0; b4 < 8; b4++) {
            float4 xv = *reinterpret_cast<const float4*>(&xs[i*BB + b4*4]);
            float xc[4] = {xv.x, xv.y, xv.z, xv.w};
            #pragma unroll
            for (int q = 0; q < 4; q++) {
                int b = b4*4 + q;
                accv[b][0] = fmaf(xc[q], wvv[0], accv[b][0]);
                accv[b][1] = fmaf(xc[q], wvv[1], accv[b][1]);
                accv[b][2] = fmaf(xc[q], wvv[2], accv[b][2]);
                accv[b][3] = fmaf(xc[q], wvv[3], accv[b][3]);
            }
        }
    }
    #pragma unroll
    for (int b = 0; b < BB; b++) {
        ushort4 o = make_ushort4(f2b(accv[b][0]), f2b(accv[b][1]),
                                 f2b(accv[b][2]), f2b(accv[b][3]));
        *reinterpret_cast<ushort4*>(&hb[(size_t)h*BLn + (size_t)b*LL + hw0]) = o;
    }
}

// ---------------- parameter precompute (ALL layers, hoisted) ----------------
__global__ __launch_bounds__(256) void k_prep1(const float* __restrict__ ldt,
        const float* __restrict__ Cp, const float* __restrict__ lAr,
        const float* __restrict__ Aimp,
        float* __restrict__ pdta, float* __restrict__ pwlc, float* __restrict__ pcd2) {
    int g = blockIdx.x*256 + threadIdx.x;   // 32768 = layer*8192 + h*32 + n
    int layer = g >> 13, h = (g >> 5) & 255, n = g & 31;
    float dt  = expf(ldt[layer*HH + h]);
    float are = -expf(lAr[(layer*HH + h)*NH + n]);
    float aim = Aimp[(layer*HH + h)*NH + n];
    float dre = are*dt, dimg = aim*dt;
    float er = expf(dre);
    float s, c; sincosf(dimg, &s, &c);
    float wre = er*c, wim = er*s;
    float den = are*are + aim*aim;
    float nre = wre - 1.f, nim = wim;
    float qre = (nre*are + nim*aim)/den;
    float qim = (nim*are - nre*aim)/den;
    float cre = Cp[((layer*HH + h)*NH + n)*2 + 0];
    float cim = Cp[((layer*HH + h)*NH + n)*2 + 1];
    float dcr = cre*qre - cim*qim;
    float dci = cre*qim + cim*qre;
    pcd2[g*2+0] = 2.f*dcr;  pcd2[g*2+1] = 2.f*dci;
    pdta[g*2+0] = dre;      pdta[g*2+1] = dimg;
    float erl = expf(dre*(float)LC);
    float sl, cl; sincosf(dimg*(float)LC, &sl, &cl);
    pwlc[g*2+0] = erl*cl;   pwlc[g*2+1] = erl*sl;
}

// kker[layer][h][m] = Re( sum_n Cd2_n * w_n^m )
__global__ __launch_bounds__(256) void k_kker(const float* __restrict__ pdta,
        const float* __restrict__ pcd2, float* __restrict__ kk) {
    int g = blockIdx.x*256 + threadIdx.x;   // 131072
    int m = g & 127, h = (g >> 7) & 255, layer = g >> 15;
    float fm = (float)m;
    float acc = 0.f;
    int base = (layer*8192 + h*32)*2;
    for (int n = 0; n < NH; n++) {
        float dre = pdta[base + n*2], dimg = pdta[base + n*2 + 1];
        float er = expf(dre*fm);
        float s, c; sincosf(dimg*fm, &s, &c);
        float dcr = pcd2[base + n*2], dci = pcd2[base + n*2 + 1];
        acc += dcr*er*c - dci*er*s;
    }
    kk[g] = acc;
}

// AstB[layer][h][r][m] bf16 : r=2n -> Re(w^(127-m)), r=2n+1 -> Im(w^(127-m))
__global__ __launch_bounds__(256) void k_bldA2(const float* __restrict__ pdta,
                                               unsigned short* __restrict__ AstB) {
    int g = blockIdx.x*256 + threadIdx.x;   // 8,388,608
    int gg = g & 2097151; int layer = g >> 21;
    int m = gg & 127; int r = (gg >> 7) & 63; int h = gg >> 13;
    int n = r >> 1;
    int pi = (layer*8192 + h*32 + n)*2;
    float e = (float)(127 - m);
    float dre = pdta[pi], dimg = pdta[pi+1];
    float er = expf(dre*e);
    float s, c; sincosf(dimg*e, &s, &c);
    AstB[g] = f2b((r & 1) ? er*s : er*c);
}

// AcvB[layer][h][j][k] bf16: k<128 Toeplitz kker[j-k]; k=128+2n Re(w^(j+1)); +1 -Im(w^(j+1))
__global__ __launch_bounds__(256) void k_bldC2(const float* __restrict__ pdta,
        const float* __restrict__ kk, unsigned short* __restrict__ AcvB) {
    int g = blockIdx.x*256 + threadIdx.x;   // 25,165,824
    int layer = g / 6291456; int gg = g - layer*6291456;
    int k = gg % 192; int j = (gg / 192) & 127; int h = gg / (192*128);
    float v;
    if (k < 128) {
        v = (j >= k) ? kk[layer*32768 + h*128 + (j - k)] : 0.f;
    } else {
        int t = k - 128; int n = t >> 1;
        int pi = (layer*8192 + h*32 + n)*2;
        float dre = pdta[pi], dimg = pdta[pi+1];
        float e = (float)(j + 1);
        float er = expf(dre*e);
        float s, c; sincosf(dimg*e, &s, &c);
        v = (t & 1) ? (-er*s) : (er*c);
    }
    AcvB[g] = f2b(v);
}

// prepack out_w (all layers) to bf16
__global__ __launch_bounds__(256) void k_prepW(const float* __restrict__ outw,
                                               unsigned short* __restrict__ Wbf) {
    int t = blockIdx.x*256 + threadIdx.x;   // 524288
    Wbf[t] = f2b(outw[t]);
}

// ---------------- fused S4D core: gA + chunk-scan + gB per (h, 8-batch group) ----------------
// grid (4, 256): ct (256 cols = 8 b x 32 c), h. 256 threads.
__global__ __launch_bounds__(256) void k_BG(const unsigned short* __restrict__ AstB,
        const unsigned short* __restrict__ AcvB, const unsigned short* __restrict__ hb,
        const float* __restrict__ pwlc, const float* __restrict__ pcd2,
        const float* __restrict__ DskL, unsigned short* __restrict__ Ybf) {
    __shared__ unsigned short Fl[256*64];   // 32 KB, XOR-swizzled [lcol][r]
    int ct = blockIdx.x, h = blockIdx.y;
    int tid = threadIdx.x;
    int w = tid >> 6, l = tid & 63;
    int l16 = l & 15, lk8 = (l >> 4)*8, e4 = (l >> 4)*4;
    int lcol0 = w*64;

    int lcolj[4]; const unsigned short* up[4];
    #pragma unroll
    for (int j = 0; j < 4; j++) {
        lcolj[j] = lcol0 + j*16 + l16;
        up[j] = hb + (size_t)h*BLn + (size_t)(ct*256 + lcolj[j])*LC;
    }

    // ---- phase A: F(64 x 256) = Ast(64x128) * U ----
    {
        f4v acc[4][4];
        #pragma unroll
        for (int i = 0; i < 4; i++)
            #pragma unroll
            for (int j = 0; j < 4; j++) acc[i][j] = (f4v){0.f,0.f,0.f,0.f};
        const unsigned short* Ab = AstB + h*8192;
        #pragma unroll
        for (int ks = 0; ks < 4; ks++) {
            int kk = ks*32 + lk8;
            s8v af[4], bfv[4];
            #pragma unroll
            for (int i = 0; i < 4; i++) af[i] = *(const s8v*)(Ab + (i*16 + l16)*128 + kk);
            #pragma unroll
            for (int j = 0; j < 4; j++) bfv[j] = *(const s8v*)(up[j] + kk);
            #pragma unroll
            for (int i = 0; i < 4; i++)
                #pragma unroll
                for (int j = 0; j < 4; j++)
                    acc[i][j] = __builtin_amdgcn_mfma_f32_16x16x32_bf16(af[i], bfv[j], acc[i][j], 0, 0, 0);
        }
        #pragma unroll
        for (int i = 0; i < 4; i++)
            #pragma unroll
            for (int j = 0; j < 4; j++) {
                int lcol = lcolj[j];
                int idx = (lcol*64 + i*16 + e4) ^ ((lcol & 7) << 3);
                ushort4 fv = make_ushort4(f2b(acc[i][j][0]), f2b(acc[i][j][1]),
                                          f2b(acc[i][j][2]), f2b(acc[i][j][3]));
                *(ushort4*)&Fl[idx] = fv;
            }
    }
    __syncthreads();

    // ---- chunk-prefix scan (in place: F -> T) ----
    {
        int n = tid & 31, bl = tid >> 5;
        int hn2 = (h*NH + n)*2;
        float wlr = pwlc[hn2], wli = pwlc[hn2+1];
        float cr  = pcd2[hn2], ci  = pcd2[hn2+1];
        float sr = 0.f, si = 0.f;
        #pragma unroll 4
        for (int c = 0; c < NC; c++) {
            int lcol = bl*32 + c;
            int idx = (lcol*64 + 2*n) ^ ((lcol & 7) << 3);
            ushort2 fv = *(ushort2*)&Fl[idx];
            float fr = b2f(fv.x), fi = b2f(fv.y);
            *(ushort2*)&Fl[idx] = make_ushort2(f2b(cr*sr - ci*si), f2b(cr*si + ci*sr));
            float nsr = fmaf(wlr, sr, fmaf(-wli, si, fr));
            si = fmaf(wlr, si, fmaf(wli, sr, fi));
            sr = nsr;
        }
    }
    __syncthreads();

    // ---- phase B: y(128 x 256) = Acv(128x192) * [U; T], skip + GELU, write bf16 ----
    float dsk = DskL[h];
    const unsigned short* Cb = AcvB + (size_t)h*24576;
    #pragma unroll
    for (int mh = 0; mh < 2; mh++) {
        f4v acc[4][4];
        #pragma unroll
        for (int i = 0; i < 4; i++)
            #pragma unroll
            for (int j = 0; j < 4; j++) acc[i][j] = (f4v){0.f,0.f,0.f,0.f};
        #pragma unroll
        for (int ks = 0; ks < 4; ks++) {        // K 0..127 from U (bf16 global)
            int kk = ks*32 + lk8;
            s8v af[4], bfv[4];
            #pragma unroll
            for (int i = 0; i < 4; i++)
                af[i] = *(const s8v*)(Cb + (mh*64 + i*16 + l16)*192 + kk);
            #pragma unroll
            for (int j = 0; j < 4; j++) bfv[j] = *(const s8v*)(up[j] + kk);
            #pragma unroll
            for (int i = 0; i < 4; i++)
                #pragma unroll
                for (int j = 0; j < 4; j++)
                    acc[i][j] = __builtin_amdgcn_mfma_f32_16x16x32_bf16(af[i], bfv[j], acc[i][j], 0, 0, 0);
        }
        #pragma unroll
        for (int ks = 0; ks < 2; ks++) {        // K 128..191 from T (LDS)
            int kk2 = ks*32 + lk8;
            s8v af[4], bfv[4];
            #pragma unroll
            for (int i = 0; i < 4; i++)
                af[i] = *(const s8v*)(Cb + (mh*64 + i*16 + l16)*192 + 128 + kk2);
            #pragma unroll
            for (int j = 0; j < 4; j++) {
                int lcol = lcolj[j];
                int idx = (lcol*64 + kk2) ^ ((lcol & 7) << 3);
                bfv[j] = *(const s8v*)&Fl[idx];
            }
            #pragma unroll
            for (int i = 0; i < 4; i++)
                #pragma unroll
                for (int j = 0; j < 4; j++)
                    acc[i][j] = __builtin_amdgcn_mfma_f32_16x16x32_bf16(af[i], bfv[j], acc[i][j], 0, 0, 0);
        }
        #pragma unroll
        for (int i = 0; i < 4; i++) {
            int m0 = mh*64 + i*16 + e4;
            #pragma unroll
            for (int j = 0; j < 4; j++) {
                ushort4 ub = *(const ushort4*)(up[j] + m0);
                float uu[4] = {b2f(ub.x), b2f(ub.y), b2f(ub.z), b2f(ub.w)};
                unsigned short ov[4];
                #pragma unroll
                for (int e = 0; e < 4; e++) {
                    float yv = acc[i][j][e] + dsk*uu[e];
                    ov[e] = f2b(0.5f*yv*(1.f + erff(yv*0.70710678118f)));
                }
                int gcol = ct*256 + lcolj[j];
                *(ushort4*)&Ybf[(size_t)h*BLn + (size_t)gcol*LC + m0] =
                    make_ushort4(ov[0], ov[1], ov[2], ov[3]);
            }
        }
    }
}

// ---------------- packY: Ybt[n][h] = Ybf[h][n] ----------------
__global__ __launch_bounds__(256) void k_packY(const unsigned short* __restrict__ Ybf,
                                               unsigned short* __restrict__ Ybt) {
    __shared__ unsigned short t[64][72];
    int n0 = (blockIdx.x >> 2) * 64;
    int h0 = (blockIdx.x & 3) * 64;
    int tid = threadIdx.x;
    int jn = (tid & 15) * 4, hr = tid >> 4;
    #pragma unroll
    for (int it = 0; it < 4; it++) {
        int hh = hr + it*16;
        ushort4 v = *(const ushort4*)&Ybf[(size_t)(h0+hh)*BLn + n0 + jn];
        t[jn+0][hh] = v.x; t[jn+1][hh] = v.y; t[jn+2][hh] = v.z; t[jn+3][hh] = v.w;
    }
    __syncthreads();
    int jh = (tid & 15) * 4, nr = tid >> 4;
    #pragma unroll
    for (int it = 0; it < 4; it++) {
        int nn = nr + it*16;
        ushort4 v = make_ushort4(t[nn][jh], t[nn][jh+1], t[nn][jh+2], t[nn][jh+3]);
        *(ushort4*)&Ybt[(size_t)(n0+nn)*HH + h0 + jh] = v;
    }
}

// ---------------- GEMM-C (MFMA): z(512 x 131072) = W*Y, fused bias+GLU+residual (bf16 RMW) ----------------
__global__ __launch_bounds__(512) void k_gC(const unsigned short* __restrict__ Wb,
        const float* __restrict__ outb, const unsigned short* __restrict__ Ybt,
        unsigned short* __restrict__ hb) {
    int nt = blockIdx.x;
    int n0 = nt*64;
    int tid = threadIdx.x;
    int w = tid >> 6, l = tid & 63;
    int l16 = l & 15, lk8 = (l >> 4) * 8, e4 = (l >> 4) * 4;
    int ra = w*32 + l16;
    f4v acc[4][4];
    #pragma unroll
    for (int i = 0; i < 4; i++)
        #pragma unroll
        for (int j = 0; j < 4; j++) acc[i][j] = (f4v){0.f,0.f,0.f,0.f};
    const unsigned short* W0 = Wb + ra*HH;
    const unsigned short* W1 = Wb + (ra+16)*HH;
    const unsigned short* W2 = Wb + (ra+256)*HH;
    const unsigned short* W3 = Wb + (ra+272)*HH;
    #pragma unroll
    for (int ks = 0; ks < 8; ks++) {
        int kk = ks*32 + lk8;
        s8v a0 = *(const s8v*)(W0 + kk);
        s8v a1 = *(const s8v*)(W1 + kk);
        s8v a2 = *(const s8v*)(W2 + kk);
        s8v a3 = *(const s8v*)(W3 + kk);
        s8v bfv[4];
        #pragma unroll
        for (int j = 0; j < 4; j++)
            bfv[j] = *(const s8v*)(Ybt + (size_t)(n0 + j*16 + l16)*HH + kk);
        #pragma unroll
        for (int j = 0; j < 4; j++) {
            acc[0][j] = __builtin_amdgcn_mfma_f32_16x16x32_bf16(a0, bfv[j], acc[0][j], 0, 0, 0);
            acc[1][j] = __builtin_amdgcn_mfma_f32_16x16x32_bf16(a1, bfv[j], acc[1][j], 0, 0, 0);
            acc[2][j] = __builtin_amdgcn_mfma_f32_16x16x32_bf16(a2, bfv[j], acc[2][j], 0, 0, 0);
            acc[3][j] = __builtin_amdgcn_mfma_f32_16x16x32_bf16(a3, bfv[j], acc[3][j], 0, 0, 0);
        }
    }
    #pragma unroll
    for (int i = 0; i < 2; i++) {
        int ob = w*32 + i*16 + e4;
        #pragma unroll
        for (int e = 0; e < 4; e++) {
            int o = ob + e;
            float ba  = outb[o];
            float bb2 = outb[o + 256];
            #pragma unroll
            for (int j = 0; j < 4; j++) {
                float za = acc[i][j][e] + ba;
                float zb = acc[i+2][j][e] + bb2;
                float sig = 1.f/(1.f + expf(-zb));
                unsigned short* hp = &hb[(size_t)o*BLn + n0 + j*16 + l16];
                *hp = f2b(b2f(*hp) + za*sig);
            }
        }
    }
}

// ---------------- decoder ----------------
__global__ __launch_bounds__(256) void k_dec(const unsigned short* __restrict__ hb,
        const float* __restrict__ dw, const float* __restrict__ db,
        float* __restrict__ out) {
    __shared__ float wsm[HH];
    int tid = threadIdx.x;
    wsm[tid] = dw[tid];
    __syncthreads();
    int g = (blockIdx.x*256 + tid)*4;
    int b = g >> 12, lp = g & 4095;
    float a0 = db[0], a1 = a0, a2 = a0, a3 = a0;
    for (int hh = 0; hh < HH; hh++) {
        float wv = wsm[hh];
        ushort4 hv = *(const ushort4*)&hb[(size_t)hh*BLn + (size_t)b*LL + lp];
        a0 = fmaf(wv, b2f(hv.x), a0);
        a1 = fmaf(wv, b2f(hv.y), a1);
        a2 = fmaf(wv, b2f(hv.z), a2);
        a3 = fmaf(wv, b2f(hv.w), a3);
    }
    *(float4*)&out[g] = make_float4(a0, a1, a2, a3);
}

extern "C" void kernel_launch(void* const* d_in, const int* in_sizes, int n_in,
                              void* d_out, int out_size, void* d_ws, size_t ws_size,
                              hipStream_t stream) {
    (void)in_sizes; (void)n_in; (void)out_size; (void)ws_size;
    const float* x    = (const float*)d_in[0];
    const float* ew   = (const float*)d_in[1];
    const float* ldt  = (const float*)d_in[2];
    const float* Cp   = (const float*)d_in[3];
    const float* lAr  = (const float*)d_in[4];
    const float* Aimp = (const float*)d_in[5];
    const float* Dsk  = (const float*)d_in[6];
    const float* outw = (const float*)d_in[7];
    const float* outb = (const float*)d_in[8];
    const float* dw   = (const float*)d_in[9];
    const float* db   = (const float*)d_in[10];

    float* ws = (float*)d_ws;
    unsigned short* hb  = (unsigned short*)ws;                  // 33,554,432 bf16  [h][b][l]
    unsigned short* Ybf = (unsigned short*)(ws + 16777216UL);   // 33,554,432 bf16  [h][n]
    unsigned short* Ybt = (unsigned short*)(ws + 33554432UL);   // 33,554,432 bf16  [n][h]
    unsigned short* AstB= (unsigned short*)(ws + 50331648UL);   //  8,388,608 bf16  (4 layers)
    unsigned short* AcvB= (unsigned short*)(ws + 54525952UL);   // 25,165,824 bf16  (4 layers)
    unsigned short* Wbf = (unsigned short*)(ws + 67108864UL);   //    524,288 bf16
    float* kk   = ws + 67371008UL;                              //    131,072 f32
    float* pdta = ws + 67502080UL;                              //     65,536 f32
    float* pwlc = ws + 67567616UL;                              //     65,536 f32
    float* pcd2 = ws + 67633152UL;                              //     65,536 f32  end ~271 MB

    k_prep1<<<128, 256, 0, stream>>>(ldt, Cp, lAr, Aimp, pdta, pwlc, pcd2);
    k_kker<<<512, 256, 0, stream>>>(pdta, pcd2, kk);
    k_bldA2<<<32768, 256, 0, stream>>>(pdta, AstB);
    k_bldC2<<<98304, 256, 0, stream>>>(pdta, kk, AcvB);
    k_prepW<<<2048, 256, 0, stream>>>(outw, Wbf);
    k_enc<<<1024, 256, 0, stream>>>(x, ew, hb);
    for (int layer = 0; layer < NLAY; layer++) {
        k_BG<<<dim3(4, 256), 256, 0, stream>>>(AstB + (size_t)layer*2097152,
                                               AcvB + (size_t)layer*6291456, hb,
                                               pwlc + layer*16384, pcd2 + layer*16384,
                                               Dsk + layer*HH, Ybf);
        k_packY<<<8192, 256, 0, stream>>>(Ybf, Ybt);
        k_gC<<<2048, 512, 0, stream>>>(Wbf + layer*131072, outb + layer*512, Ybt, hb);
    }
    k_dec<<<128, 256, 0, stream>>>(hb, dw, db, (float*)d_out);
}

// Round 5
// 1273.702 us; speedup vs baseline: 2.7111x; 1.1831x over previous
//
#include <hip/hip_runtime.h>
#include <hip/hip_bf16.h>
#include <math.h>

#define BB   32
#define DIN  100
#define HH   256
#define NLAY 4
#define NH   32
#define LL   4096
#define LC   128
#define NC   32
#define HL   (HH*LL)   // 1048576
#define BLn  (BB*LL)   // 131072

typedef __attribute__((ext_vector_type(8))) short s8v;
typedef __attribute__((ext_vector_type(4))) float f4v;

__device__ inline unsigned short f2b(float x) {
    unsigned int u = __float_as_uint(x);
    unsigned int r = (u + 0x7fffu + ((u >> 16) & 1u)) >> 16;
    return (unsigned short)r;
}
__device__ inline float b2f(unsigned short u) {
    return __uint_as_float(((unsigned int)u) << 16);
}

// ---------------- encoder: hb[h][b][l] bf16 = sum_i x[b][i]*ew[i][h][l] ----------------
__global__ __launch_bounds__(256) void k_enc(const float* __restrict__ x,
                                             const float* __restrict__ ew,
                                             unsigned short* __restrict__ hb) {
    __shared__ __align__(16) float xs[DIN*BB];
    int tid = threadIdx.x;
    for (int idx = tid; idx < DIN*BB; idx += 256) {
        int b = idx & 31, i = idx >> 5;
        xs[i*BB + b] = x[b*DIN + i];
    }
    __syncthreads();
    int gid0 = (blockIdx.x*256 + tid) * 4;   // (h,hw) flattened
    int h = gid0 >> 12, hw0 = gid0 & 4095;
    float accv[BB][4];
    #pragma unroll
    for (int b = 0; b < BB; b++) { accv[b][0]=0.f; accv[b][1]=0.f; accv[b][2]=0.f; accv[b][3]=0.f; }
    for (int i = 0; i < DIN; i++) {
        float4 wv = *reinterpret_cast<const float4*>(&ew[(size_t)i*HL + gid0]);
        float wvv[4] = {wv.x, wv.y, wv.z, wv.w};
        #pragma unroll
        for (int b4 = 0; b4 < 8; b4++) {
            float4 xv = *reinterpret_cast<const float4*>(&xs[i*BB + b4*4]);
            float xc[4] = {xv.x, xv.y, xv.z, xv.w};
            #pragma unroll
            for (int q = 0; q < 4; q++) {
                int b = b4*4 + q;
                accv[b][0] = fmaf(xc[q], wvv[0], accv[b][0]);
                accv[b][1] = fmaf(xc[q], wvv[1], accv[b][1]);
                accv[b][2] = fmaf(xc[q], wvv[2], accv[b][2]);
                accv[b][3] = fmaf(xc[q], wvv[3], accv[b][3]);
            }
        }
    }
    #pragma unroll
    for (int b = 0; b < BB; b++) {
        ushort4 o = make_ushort4(f2b(accv[b][0]), f2b(accv[b][1]),
                                 f2b(accv[b][2]), f2b(accv[b][3]));
        *reinterpret_cast<ushort4*>(&hb[(size_t)h*BLn + (size_t)b*LL + hw0]) = o;
    }
}

// ---------------- parameter precompute (ALL layers, hoisted) ----------------
__global__ __launch_bounds__(256) void k_prep1(const float* __restrict__ ldt,
        const float* __restrict__ Cp, const float* __restrict__ lAr,
        const float* __restrict__ Aimp,
        float* __restrict__ pdta, float* __restrict__ pwlc, float* __restrict__ pcd2) {
    int g = blockIdx.x*256 + threadIdx.x;   // 32768 = layer*8192 + h*32 + n
    int layer = g >> 13, h = (g >> 5) & 255, n = g & 31;
    float dt  = expf(ldt[layer*HH + h]);
    float are = -expf(lAr[(layer*HH + h)*NH + n]);
    float aim = Aimp[(layer*HH + h)*NH + n];
    float dre = are*dt, dimg = aim*dt;
    float er = expf(dre);
    float s, c; sincosf(dimg, &s, &c);
    float wre = er*c, wim = er*s;
    float den = are*are + aim*aim;
    float nre = wre - 1.f, nim = wim;
    float qre = (nre*are + nim*aim)/den;
    float qim = (nim*are - nre*aim)/den;
    float cre = Cp[((layer*HH + h)*NH + n)*2 + 0];
    float cim = Cp[((layer*HH + h)*NH + n)*2 + 1];
    float dcr = cre*qre - cim*qim;
    float dci = cre*qim + cim*qre;
    pcd2[g*2+0] = 2.f*dcr;  pcd2[g*2+1] = 2.f*dci;
    pdta[g*2+0] = dre;      pdta[g*2+1] = dimg;
    float erl = expf(dre*(float)LC);
    float sl, cl; sincosf(dimg*(float)LC, &sl, &cl);
    pwlc[g*2+0] = erl*cl;   pwlc[g*2+1] = erl*sl;
}

// kker[layer][h][m] = Re( sum_n Cd2_n * w_n^m )
__global__ __launch_bounds__(256) void k_kker(const float* __restrict__ pdta,
        const float* __restrict__ pcd2, float* __restrict__ kk) {
    int g = blockIdx.x*256 + threadIdx.x;   // 131072
    int m = g & 127;
    float fm = (float)m;
    float acc = 0.f;
    int base = (g >> 7) * 32 * 2;
    for (int n = 0; n < NH; n++) {
        float dre = pdta[base + n*2], dimg = pdta[base + n*2 + 1];
        float er = expf(dre*fm);
        float s, c; sincosf(dimg*fm, &s, &c);
        float dcr = pcd2[base + n*2], dci = pcd2[base + n*2 + 1];
        acc += dcr*er*c - dci*er*s;
    }
    kk[g] = acc;
}

// AstB[layer][h][r][m] bf16 : r=2n -> Re(w^(127-m)), r=2n+1 -> Im(w^(127-m))
__global__ __launch_bounds__(256) void k_bldA2(const float* __restrict__ pdta,
                                               unsigned short* __restrict__ AstB) {
    int g = blockIdx.x*256 + threadIdx.x;   // 8,388,608
    int gg = g & 2097151; int layer = g >> 21;
    int m = gg & 127; int r = (gg >> 7) & 63; int h = gg >> 13;
    int n = r >> 1;
    int pi = (layer*8192 + h*32 + n)*2;
    float e = (float)(127 - m);
    float dre = pdta[pi], dimg = pdta[pi+1];
    float er = expf(dre*e);
    float s, c; sincosf(dimg*e, &s, &c);
    AstB[g] = f2b((r & 1) ? er*s : er*c);
}

// AcvB[layer][h][j][k] bf16: k<128 Toeplitz kker[j-k]; k=128+2n Re(w^(j+1)); +1 -Im(w^(j+1))
__global__ __launch_bounds__(256) void k_bldC2(const float* __restrict__ pdta,
        const float* __restrict__ kk, unsigned short* __restrict__ AcvB) {
    int g = blockIdx.x*256 + threadIdx.x;   // 25,165,824
    int layer = g / 6291456; int gg = g - layer*6291456;
    int k = gg % 192; int j = (gg / 192) & 127; int h = gg / (192*128);
    float v;
    if (k < 128) {
        v = (j >= k) ? kk[layer*32768 + h*128 + (j - k)] : 0.f;
    } else {
        int t = k - 128; int n = t >> 1;
        int pi = (layer*8192 + h*32 + n)*2;
        float dre = pdta[pi], dimg = pdta[pi+1];
        float e = (float)(j + 1);
        float er = expf(dre*e);
        float s, c; sincosf(dimg*e, &s, &c);
        v = (t & 1) ? (-er*s) : (er*c);
    }
    AcvB[g] = f2b(v);
}

// prepack out_w (all layers) to bf16
__global__ __launch_bounds__(256) void k_prepW(const float* __restrict__ outw,
                                               unsigned short* __restrict__ Wbf) {
    int t = blockIdx.x*256 + threadIdx.x;   // 524288
    Wbf[t] = f2b(outw[t]);
}

// ---------------- fused S4D core: gA + chunk-scan + gB per (h, 8-batch group) ----------------
__global__ __launch_bounds__(256) void k_BG(const unsigned short* __restrict__ AstB,
        const unsigned short* __restrict__ AcvB, const unsigned short* __restrict__ hb,
        const float* __restrict__ pwlc, const float* __restrict__ pcd2,
        const float* __restrict__ DskL, unsigned short* __restrict__ Ybf) {
    __shared__ unsigned short Fl[256*64];   // 32 KB, XOR-swizzled [lcol][r]
    int ct = blockIdx.x, h = blockIdx.y;
    int tid = threadIdx.x;
    int w = tid >> 6, l = tid & 63;
    int l16 = l & 15, lk8 = (l >> 4)*8, e4 = (l >> 4)*4;
    int lcol0 = w*64;

    int lcolj[4]; const unsigned short* up[4];
    #pragma unroll
    for (int j = 0; j < 4; j++) {
        lcolj[j] = lcol0 + j*16 + l16;
        up[j] = hb + (size_t)h*BLn + (size_t)(ct*256 + lcolj[j])*LC;
    }

    // ---- phase A: F(64 x 256) = Ast(64x128) * U ----
    {
        f4v acc[4][4];
        #pragma unroll
        for (int i = 0; i < 4; i++)
            #pragma unroll
            for (int j = 0; j < 4; j++) acc[i][j] = (f4v){0.f,0.f,0.f,0.f};
        const unsigned short* Ab = AstB + h*8192;
        #pragma unroll
        for (int ks = 0; ks < 4; ks++) {
            int kk = ks*32 + lk8;
            s8v af[4], bfv[4];
            #pragma unroll
            for (int i = 0; i < 4; i++) af[i] = *(const s8v*)(Ab + (i*16 + l16)*128 + kk);
            #pragma unroll
            for (int j = 0; j < 4; j++) bfv[j] = *(const s8v*)(up[j] + kk);
            #pragma unroll
            for (int i = 0; i < 4; i++)
                #pragma unroll
                for (int j = 0; j < 4; j++)
                    acc[i][j] = __builtin_amdgcn_mfma_f32_16x16x32_bf16(af[i], bfv[j], acc[i][j], 0, 0, 0);
        }
        #pragma unroll
        for (int i = 0; i < 4; i++)
            #pragma unroll
            for (int j = 0; j < 4; j++) {
                int lcol = lcolj[j];
                int idx = (lcol*64 + i*16 + e4) ^ ((lcol & 7) << 3);
                ushort4 fv = make_ushort4(f2b(acc[i][j][0]), f2b(acc[i][j][1]),
                                          f2b(acc[i][j][2]), f2b(acc[i][j][3]));
                *(ushort4*)&Fl[idx] = fv;
            }
    }
    __syncthreads();

    // ---- chunk-prefix scan (in place: F -> T) ----
    {
        int n = tid & 31, bl = tid >> 5;
        int hn2 = (h*NH + n)*2;
        float wlr = pwlc[hn2], wli = pwlc[hn2+1];
        float cr  = pcd2[hn2], ci  = pcd2[hn2+1];
        float sr = 0.f, si = 0.f;
        #pragma unroll 4
        for (int c = 0; c < NC; c++) {
            int lcol = bl*32 + c;
            int idx = (lcol*64 + 2*n) ^ ((lcol & 7) << 3);
            ushort2 fv = *(ushort2*)&Fl[idx];
            float fr = b2f(fv.x), fi = b2f(fv.y);
            *(ushort2*)&Fl[idx] = make_ushort2(f2b(cr*sr - ci*si), f2b(cr*si + ci*sr));
            float nsr = fmaf(wlr, sr, fmaf(-wli, si, fr));
            si = fmaf(wlr, si, fmaf(wli, sr, fi));
            sr = nsr;
        }
    }
    __syncthreads();

    // ---- phase B: y(128 x 256) = Acv(128x192) * [U; T], skip + GELU, write bf16 ----
    float dsk = DskL[h];
    const unsigned short* Cb = AcvB + (size_t)h*24576;
    #pragma unroll
    for (int mh = 0; mh < 2; mh++) {
        f4v acc[4][4];
        #pragma unroll
        for (int i = 0; i < 4; i++)
            #pragma unroll
            for (int j = 0; j < 4; j++) acc[i][j] = (f4v){0.f,0.f,0.f,0.f};
        #pragma unroll
        for (int ks = 0; ks < 4; ks++) {        // K 0..127 from U (bf16 global)
            int kk = ks*32 + lk8;
            s8v af[4], bfv[4];
            #pragma unroll
            for (int i = 0; i < 4; i++)
                af[i] = *(const s8v*)(Cb + (mh*64 + i*16 + l16)*192 + kk);
            #pragma unroll
            for (int j = 0; j < 4; j++) bfv[j] = *(const s8v*)(up[j] + kk);
            #pragma unroll
            for (int i = 0; i < 4; i++)
                #pragma unroll
                for (int j = 0; j < 4; j++)
                    acc[i][j] = __builtin_amdgcn_mfma_f32_16x16x32_bf16(af[i], bfv[j], acc[i][j], 0, 0, 0);
        }
        #pragma unroll
        for (int ks = 0; ks < 2; ks++) {        // K 128..191 from T (LDS)
            int kk2 = ks*32 + lk8;
            s8v af[4], bfv[4];
            #pragma unroll
            for (int i = 0; i < 4; i++)
                af[i] = *(const s8v*)(Cb + (mh*64 + i*16 + l16)*192 + 128 + kk2);
            #pragma unroll
            for (int j = 0; j < 4; j++) {
                int lcol = lcolj[j];
                int idx = (lcol*64 + kk2) ^ ((lcol & 7) << 3);
                bfv[j] = *(const s8v*)&Fl[idx];
            }
            #pragma unroll
            for (int i = 0; i < 4; i++)
                #pragma unroll
                for (int j = 0; j < 4; j++)
                    acc[i][j] = __builtin_amdgcn_mfma_f32_16x16x32_bf16(af[i], bfv[j], acc[i][j], 0, 0, 0);
        }
        #pragma unroll
        for (int i = 0; i < 4; i++) {
            int m0 = mh*64 + i*16 + e4;
            #pragma unroll
            for (int j = 0; j < 4; j++) {
                ushort4 ub = *(const ushort4*)(up[j] + m0);
                float uu[4] = {b2f(ub.x), b2f(ub.y), b2f(ub.z), b2f(ub.w)};
                unsigned short ov[4];
                #pragma unroll
                for (int e = 0; e < 4; e++) {
                    float yv = acc[i][j][e] + dsk*uu[e];
                    ov[e] = f2b(0.5f*yv*(1.f + erff(yv*0.70710678118f)));
                }
                int gcol = ct*256 + lcolj[j];
                *(ushort4*)&Ybf[(size_t)h*BLn + (size_t)gcol*LC + m0] =
                    make_ushort4(ov[0], ov[1], ov[2], ov[3]);
            }
        }
    }
}

// ---------------- GEMM-C (MFMA): z = W*Y with in-kernel Y transpose (LDS),
//                  fused bias+GLU+residual; last layer fuses decoder ----------------
__global__ __launch_bounds__(512) void k_gC2(const unsigned short* __restrict__ Wb,
        const float* __restrict__ outb, const unsigned short* __restrict__ Ybf,
        unsigned short* __restrict__ hb, const float* __restrict__ dw,
        const float* __restrict__ db, float* __restrict__ outp, int doDec) {
    __shared__ __align__(16) unsigned char smem[34048];
    unsigned short* Bl = (unsigned short*)smem;      // [64 n][258 h], XOR-swizzled
    float* part = (float*)smem;                      // aliased: [64 n][33 groups]
    int nt = blockIdx.x;
    int n0 = nt*64;
    int tid = threadIdx.x;

    // stage + transpose Y tile: rows h=0..255, cols n0..n0+63
    {
        int jn = (tid & 15) * 4;
        int hq = tid >> 4;          // 0..31
        #pragma unroll
        for (int hb8 = 0; hb8 < 8; hb8++) {
            int h = hb8*32 + hq;
            ushort4 v = *(const ushort4*)&Ybf[(size_t)h*BLn + n0 + jn];
            unsigned short vv[4] = {v.x, v.y, v.z, v.w};
            #pragma unroll
            for (int i = 0; i < 4; i++) {
                int row = jn + i;
                Bl[row*258 + (h ^ ((row & 7) << 3))] = vv[i];
            }
        }
    }
    __syncthreads();

    int w = tid >> 6, l = tid & 63;
    int l16 = l & 15, lk8 = (l >> 4) * 8, e4 = (l >> 4) * 4;
    int ra = w*32 + l16;
    int swz = (l16 & 7) << 3;
    f4v acc[4][4];
    #pragma unroll
    for (int i = 0; i < 4; i++)
        #pragma unroll
        for (int j = 0; j < 4; j++) acc[i][j] = (f4v){0.f,0.f,0.f,0.f};
    const unsigned short* W0 = Wb + ra*HH;
    const unsigned short* W1 = Wb + (ra+16)*HH;
    const unsigned short* W2 = Wb + (ra+256)*HH;
    const unsigned short* W3 = Wb + (ra+272)*HH;
    #pragma unroll
    for (int ks = 0; ks < 8; ks++) {
        int kk = ks*32 + lk8;
        s8v a0 = *(const s8v*)(W0 + kk);
        s8v a1 = *(const s8v*)(W1 + kk);
        s8v a2 = *(const s8v*)(W2 + kk);
        s8v a3 = *(const s8v*)(W3 + kk);
        s8v bfv[4];
        #pragma unroll
        for (int j = 0; j < 4; j++) {
            int row = j*16 + l16;
            bfv[j] = *(const s8v*)&Bl[row*258 + (kk ^ swz)];
        }
        #pragma unroll
        for (int j = 0; j < 4; j++) {
            acc[0][j] = __builtin_amdgcn_mfma_f32_16x16x32_bf16(a0, bfv[j], acc[0][j], 0, 0, 0);
            acc[1][j] = __builtin_amdgcn_mfma_f32_16x16x32_bf16(a1, bfv[j], acc[1][j], 0, 0, 0);
            acc[2][j] = __builtin_amdgcn_mfma_f32_16x16x32_bf16(a2, bfv[j], acc[2][j], 0, 0, 0);
            acc[3][j] = __builtin_amdgcn_mfma_f32_16x16x32_bf16(a3, bfv[j], acc[3][j], 0, 0, 0);
        }
    }

    float pj[4] = {0.f, 0.f, 0.f, 0.f};
    #pragma unroll
    for (int i = 0; i < 2; i++) {
        int ob = w*32 + i*16 + e4;
        #pragma unroll
        for (int e = 0; e < 4; e++) {
            int o = ob + e;
            float ba  = outb[o];
            float bb2 = outb[o + 256];
            float dwo = doDec ? dw[o] : 0.f;
            #pragma unroll
            for (int j = 0; j < 4; j++) {
                float za = acc[i][j][e] + ba;
                float zb = acc[i+2][j][e] + bb2;
                float sig = 1.f/(1.f + expf(-zb));
                unsigned short* hp = &hb[(size_t)o*BLn + n0 + j*16 + l16];
                float hnew = b2f(*hp) + za*sig;
                if (doDec) {
                    pj[j] = fmaf(dwo, hnew, pj[j]);
                } else {
                    *hp = f2b(hnew);
                }
            }
        }
    }

    if (doDec) {
        __syncthreads();   // all waves done reading Bl
        int g32 = w*4 + (l >> 4);
        #pragma unroll
        for (int j = 0; j < 4; j++) {
            int nl = j*16 + l16;
            part[nl*33 + g32] = pj[j];
        }
        __syncthreads();
        if (tid < 64) {
            float s = db[0];
            #pragma unroll
            for (int g = 0; g < 32; g++) s += part[tid*33 + g];
            outp[n0 + tid] = s;
        }
    }
}

extern "C" void kernel_launch(void* const* d_in, const int* in_sizes, int n_in,
                              void* d_out, int out_size, void* d_ws, size_t ws_size,
                              hipStream_t stream) {
    (void)in_sizes; (void)n_in; (void)out_size; (void)ws_size;
    const float* x    = (const float*)d_in[0];
    const float* ew   = (const float*)d_in[1];
    const float* ldt  = (const float*)d_in[2];
    const float* Cp   = (const float*)d_in[3];
    const float* lAr  = (const float*)d_in[4];
    const float* Aimp = (const float*)d_in[5];
    const float* Dsk  = (const float*)d_in[6];
    const float* outw = (const float*)d_in[7];
    const float* outb = (const float*)d_in[8];
    const float* dw   = (const float*)d_in[9];
    const float* db   = (const float*)d_in[10];

    float* ws = (float*)d_ws;
    unsigned short* hb  = (unsigned short*)ws;                  // 33,554,432 bf16  [h][b][l]
    unsigned short* Ybf = (unsigned short*)(ws + 16777216UL);   // 33,554,432 bf16  [h][n] linear
    unsigned short* AstB= (unsigned short*)(ws + 33554432UL);   //  8,388,608 bf16  (4 layers)
    unsigned short* AcvB= (unsigned short*)(ws + 37748736UL);   // 25,165,824 bf16  (4 layers)
    unsigned short* Wbf = (unsigned short*)(ws + 50331648UL);   //    524,288 bf16
    float* kk   = ws + 50593792UL;                              //    131,072 f32
    float* pdta = ws + 50724864UL;                              //     65,536 f32
    float* pwlc = ws + 50790400UL;                              //     65,536 f32
    float* pcd2 = ws + 50855936UL;                              //     65,536 f32  end ~204 MB

    k_prep1<<<128, 256, 0, stream>>>(ldt, Cp, lAr, Aimp, pdta, pwlc, pcd2);
    k_kker<<<512, 256, 0, stream>>>(pdta, pcd2, kk);
    k_bldA2<<<32768, 256, 0, stream>>>(pdta, AstB);
    k_bldC2<<<98304, 256, 0, stream>>>(pdta, kk, AcvB);
    k_prepW<<<2048, 256, 0, stream>>>(outw, Wbf);
    k_enc<<<1024, 256, 0, stream>>>(x, ew, hb);
    for (int layer = 0; layer < NLAY; layer++) {
        k_BG<<<dim3(4, 256), 256, 0, stream>>>(AstB + (size_t)layer*2097152,
                                               AcvB + (size_t)layer*6291456, hb,
                                               pwlc + layer*16384, pcd2 + layer*16384,
                                               Dsk + layer*HH, Ybf);
        k_gC2<<<2048, 512, 0, stream>>>(Wbf + layer*131072, outb + layer*512, Ybf, hb,
                                        dw, db, (float*)d_out, (layer == NLAY-1) ? 1 : 0);
    }
}

// Round 6
// 993.029 us; speedup vs baseline: 3.4773x; 1.2826x over previous
//
#include <hip/hip_runtime.h>
#include <hip/hip_bf16.h>
#include <math.h>

#define BB   32
#define DIN  100
#define HH   256
#define NLAY 4
#define NH   32
#define LL   4096
#define LC   128
#define NC   32
#define HL   (HH*LL)   // 1048576
#define BLn  (BB*LL)   // 131072

typedef __attribute__((ext_vector_type(8))) short s8v;
typedef __attribute__((ext_vector_type(4))) float f4v;

__device__ inline unsigned short f2b(float x) {
    unsigned int u = __float_as_uint(x);
    unsigned int r = (u + 0x7fffu + ((u >> 16) & 1u)) >> 16;
    return (unsigned short)r;
}
__device__ inline float b2f(unsigned short u) {
    return __uint_as_float(((unsigned int)u) << 16);
}

// ---------------- encoder (MFMA): hb[h][b][l] = sum_i x[b][i]*ew[i][h][l] ----------------
// block = 256 consecutive hl (one h); D[b][hl] via 16x16x32 bf16 MFMA, K=100 padded to 128.
__global__ __launch_bounds__(256) void k_enc(const float* __restrict__ x,
                                             const float* __restrict__ ew,
                                             unsigned short* __restrict__ hb) {
    __shared__ unsigned short xs[BB*128];    // [b][k] bf16, swizzled, zero-padded
    __shared__ unsigned short ot[BB*264];    // [b][hl_local] transpose-out buffer
    int tid = threadIdx.x;
    for (int idx = tid; idx < BB*128; idx += 256) {
        int b = idx >> 7, k = idx & 127;
        float v = (k < DIN) ? x[b*DIN + k] : 0.f;
        int slot = (k >> 3) ^ (b & 7);
        xs[b*128 + slot*8 + (k & 7)] = f2b(v);
    }
    __syncthreads();
    int hl0 = blockIdx.x * 256;
    int h = hl0 >> 12, l0 = hl0 & 4095;
    int w = tid >> 6, l = tid & 63;
    int l16 = l & 15, lk8 = (l >> 4) * 8, e4 = (l >> 4) * 4;
    int col0 = w * 64;
    f4v acc[2][4];
    #pragma unroll
    for (int i = 0; i < 2; i++)
        #pragma unroll
        for (int j = 0; j < 4; j++) acc[i][j] = (f4v){0.f,0.f,0.f,0.f};
    #pragma unroll
    for (int ks = 0; ks < 4; ks++) {
        int kb = ks*32 + lk8;
        int sl0 = kb >> 3;
        s8v a0 = *(const s8v*)&xs[l16*128 + (sl0 ^ (l16 & 7))*8];
        s8v a1 = *(const s8v*)&xs[(16 + l16)*128 + (sl0 ^ (l16 & 7))*8];
        #pragma unroll
        for (int j = 0; j < 4; j++) {
            int hl = hl0 + col0 + j*16 + l16;
            const float* ep = ew + (size_t)kb * HL + hl;
            s8v bf;
            #pragma unroll
            for (int q = 0; q < 8; q++) {
                float ev = (kb + q < DIN) ? ep[(size_t)q * HL] : 0.f;
                bf[q] = (short)f2b(ev);
            }
            acc[0][j] = __builtin_amdgcn_mfma_f32_16x16x32_bf16(a0, bf, acc[0][j], 0, 0, 0);
            acc[1][j] = __builtin_amdgcn_mfma_f32_16x16x32_bf16(a1, bf, acc[1][j], 0, 0, 0);
        }
    }
    #pragma unroll
    for (int i = 0; i < 2; i++)
        #pragma unroll
        for (int j = 0; j < 4; j++) {
            int cl = col0 + j*16 + l16;
            #pragma unroll
            for (int e = 0; e < 4; e++) {
                int b = i*16 + e4 + e;
                ot[b*264 + cl] = f2b(acc[i][j][e]);
            }
        }
    __syncthreads();
    {
        int b = tid >> 3, off = (tid & 7) * 32;
        const unsigned short* src = &ot[b*264 + off];
        unsigned short* dst = &hb[(size_t)h*BLn + (size_t)b*LL + l0 + off];
        #pragma unroll
        for (int q = 0; q < 4; q++)
            *(s8v*)(dst + q*8) = *(const s8v*)(src + q*8);
    }
}

// ---------------- parameter precompute (ALL layers) ----------------
__global__ __launch_bounds__(256) void k_prep1(const float* __restrict__ ldt,
        const float* __restrict__ Cp, const float* __restrict__ lAr,
        const float* __restrict__ Aimp,
        float* __restrict__ pdta, float* __restrict__ pwlc, float* __restrict__ pcd2) {
    int g = blockIdx.x*256 + threadIdx.x;   // 32768 = layer*8192 + h*32 + n
    int layer = g >> 13, h = (g >> 5) & 255, n = g & 31;
    float dt  = expf(ldt[layer*HH + h]);
    float are = -expf(lAr[(layer*HH + h)*NH + n]);
    float aim = Aimp[(layer*HH + h)*NH + n];
    float dre = are*dt, dimg = aim*dt;
    float er = expf(dre);
    float s, c; sincosf(dimg, &s, &c);
    float wre = er*c, wim = er*s;
    float den = are*are + aim*aim;
    float nre = wre - 1.f, nim = wim;
    float qre = (nre*are + nim*aim)/den;
    float qim = (nim*are - nre*aim)/den;
    float cre = Cp[((layer*HH + h)*NH + n)*2 + 0];
    float cim = Cp[((layer*HH + h)*NH + n)*2 + 1];
    float dcr = cre*qre - cim*qim;
    float dci = cre*qim + cim*qre;
    pcd2[g*2+0] = 2.f*dcr;  pcd2[g*2+1] = 2.f*dci;
    pdta[g*2+0] = dre;      pdta[g*2+1] = dimg;
    float erl = expf(dre*(float)LC);
    float sl, cl; sincosf(dimg*(float)LC, &sl, &cl);
    pwlc[g*2+0] = erl*cl;   pwlc[g*2+1] = erl*sl;
}

// ---------------- merged builder: kker (LDS) + AstB + AcvB per (layer,h) block ----------------
__global__ __launch_bounds__(256) void k_bldAll(const float* __restrict__ pdta,
        const float* __restrict__ pcd2, unsigned short* __restrict__ AstB,
        unsigned short* __restrict__ AcvB) {
    __shared__ float dre_s[NH], dim_s[NH], c2r[NH], c2i[NH];
    __shared__ float kkl[LC];
    int bid = blockIdx.x;          // layer*256 + h
    int tid = threadIdx.x;
    int pbase = bid * 64;          // = (layer*8192 + h*32)*2
    if (tid < NH) {
        dre_s[tid] = pdta[pbase + tid*2];
        dim_s[tid] = pdta[pbase + tid*2 + 1];
        c2r[tid]   = pcd2[pbase + tid*2];
        c2i[tid]   = pcd2[pbase + tid*2 + 1];
    }
    __syncthreads();
    if (tid < LC) {
        float fm = (float)tid;
        float acc = 0.f;
        for (int n = 0; n < NH; n++) {
            float er = expf(dre_s[n]*fm);
            float s, c; sincosf(dim_s[n]*fm, &s, &c);
            acc += c2r[n]*er*c - c2i[n]*er*s;
        }
        kkl[tid] = acc;
    }
    __syncthreads();
    unsigned short* As = AstB + (size_t)bid * 8192;
    for (int idx = tid; idx < 8192; idx += 256) {
        int r = idx >> 7, m = idx & 127, n = r >> 1;
        float e = (float)(127 - m);
        float er = expf(dre_s[n]*e);
        float s, c; sincosf(dim_s[n]*e, &s, &c);
        As[idx] = f2b((r & 1) ? er*s : er*c);
    }
    unsigned short* Ac = AcvB + (size_t)bid * 24576;
    for (int idx = tid; idx < 24576; idx += 256) {
        int j = idx / 192, k = idx - j*192;
        float v;
        if (k < 128) {
            v = (j >= k) ? kkl[j - k] : 0.f;
        } else {
            int n = (k - 128) >> 1;
            float e = (float)(j + 1);
            float er = expf(dre_s[n]*e);
            float s, c; sincosf(dim_s[n]*e, &s, &c);
            v = ((k - 128) & 1) ? (-er*s) : (er*c);
        }
        Ac[idx] = f2b(v);
    }
}

// prepack out_w (all layers) to bf16
__global__ __launch_bounds__(256) void k_prepW(const float* __restrict__ outw,
                                               unsigned short* __restrict__ Wbf) {
    int t = blockIdx.x*256 + threadIdx.x;   // 524288
    Wbf[t] = f2b(outw[t]);
}

// ---------------- fused S4D core: U staged once in swizzled LDS; gA + scan + gB ----------------
// grid (8, 256): ct (128 cols = 4 b x 32 c), h. 256 threads = 4 waves.
__global__ __launch_bounds__(256) void k_BG(const unsigned short* __restrict__ AstB,
        const unsigned short* __restrict__ AcvB, const unsigned short* __restrict__ hb,
        const float* __restrict__ pwlc, const float* __restrict__ pcd2,
        const float* __restrict__ DskL, unsigned short* __restrict__ Ybf) {
    __shared__ unsigned short Ul[128*128];   // 32 KB [col][k] swizzled: slot = k8 ^ (col&7)
    __shared__ unsigned short Fl[128*64];    // 16 KB [lcol][r]  swizzled: ^((lcol&7)<<3)
    int ct = blockIdx.x, h = blockIdx.y;
    int tid = threadIdx.x;
    const unsigned short* ub = hb + (size_t)h*BLn + (size_t)ct*128*LC;
    #pragma unroll
    for (int it = 0; it < 8; it++) {
        int idx = it*256 + tid;
        int col = idx >> 4, slot = idx & 15;
        s8v v = *(const s8v*)(ub + col*LC + slot*8);
        *(s8v*)&Ul[col*128 + (slot ^ (col & 7))*8] = v;
    }
    __syncthreads();
    int w = tid >> 6, l = tid & 63;
    int l16 = l & 15, lk8 = (l >> 4)*8, e4 = (l >> 4)*4;
    int k8q = l >> 4;

    // ---- phase A: F(64 x 128) = Ast(64x128) * U ; wave w owns rows w*16..+15 ----
    {
        f4v acc[8];
        #pragma unroll
        for (int j = 0; j < 8; j++) acc[j] = (f4v){0.f,0.f,0.f,0.f};
        const unsigned short* Ab = AstB + (size_t)h*8192 + (w*16 + l16)*128;
        #pragma unroll
        for (int ks = 0; ks < 4; ks++) {
            s8v af = *(const s8v*)(Ab + ks*32 + lk8);
            int k8 = ks*4 + k8q;
            #pragma unroll
            for (int j = 0; j < 8; j++) {
                int col = j*16 + l16;
                s8v bf = *(const s8v*)&Ul[col*128 + (k8 ^ (col & 7))*8];
                acc[j] = __builtin_amdgcn_mfma_f32_16x16x32_bf16(af, bf, acc[j], 0, 0, 0);
            }
        }
        #pragma unroll
        for (int j = 0; j < 8; j++) {
            int col = j*16 + l16;
            int idx = (col*64 + w*16 + e4) ^ ((col & 7) << 3);
            *(ushort4*)&Fl[idx] = make_ushort4(f2b(acc[j][0]), f2b(acc[j][1]),
                                               f2b(acc[j][2]), f2b(acc[j][3]));
        }
    }
    __syncthreads();

    // ---- chunk-prefix scan (in place: F -> T) ----
    if (tid < 128) {
        int n = tid & 31, bl = tid >> 5;
        int hn2 = (h*NH + n)*2;
        float wlr = pwlc[hn2], wli = pwlc[hn2+1];
        float cr  = pcd2[hn2], ci  = pcd2[hn2+1];
        float sr = 0.f, si = 0.f;
        #pragma unroll 4
        for (int c = 0; c < NC; c++) {
            int lcol = bl*32 + c;
            int idx = (lcol*64 + 2*n) ^ ((lcol & 7) << 3);
            ushort2 fv = *(ushort2*)&Fl[idx];
            float fr = b2f(fv.x), fi = b2f(fv.y);
            *(ushort2*)&Fl[idx] = make_ushort2(f2b(cr*sr - ci*si), f2b(cr*si + ci*sr));
            float nsr = fmaf(wlr, sr, fmaf(-wli, si, fr));
            si = fmaf(wlr, si, fmaf(wli, sr, fi));
            sr = nsr;
        }
    }
    __syncthreads();

    // ---- phase B: y(128 x 128) = Acv(128x192) * [U; T] ; wave w owns rows w*32..+31 ----
    float dsk = DskL[h];
    const unsigned short* Cb = AcvB + (size_t)h*24576;
    f4v acc[2][8];
    #pragma unroll
    for (int i = 0; i < 2; i++)
        #pragma unroll
        for (int j = 0; j < 8; j++) acc[i][j] = (f4v){0.f,0.f,0.f,0.f};
    #pragma unroll
    for (int ks = 0; ks < 4; ks++) {
        s8v af0 = *(const s8v*)(Cb + (w*32 + l16)*192 + ks*32 + lk8);
        s8v af1 = *(const s8v*)(Cb + (w*32 + 16 + l16)*192 + ks*32 + lk8);
        int k8 = ks*4 + k8q;
        #pragma unroll
        for (int j = 0; j < 8; j++) {
            int col = j*16 + l16;
            s8v bf = *(const s8v*)&Ul[col*128 + (k8 ^ (col & 7))*8];
            acc[0][j] = __builtin_amdgcn_mfma_f32_16x16x32_bf16(af0, bf, acc[0][j], 0, 0, 0);
            acc[1][j] = __builtin_amdgcn_mfma_f32_16x16x32_bf16(af1, bf, acc[1][j], 0, 0, 0);
        }
    }
    #pragma unroll
    for (int ks = 0; ks < 2; ks++) {
        s8v af0 = *(const s8v*)(Cb + (w*32 + l16)*192 + 128 + ks*32 + lk8);
        s8v af1 = *(const s8v*)(Cb + (w*32 + 16 + l16)*192 + 128 + ks*32 + lk8);
        int kk2 = ks*32 + lk8;
        #pragma unroll
        for (int j = 0; j < 8; j++) {
            int col = j*16 + l16;
            int idx = (col*64 + kk2) ^ ((col & 7) << 3);
            s8v bf = *(const s8v*)&Fl[idx];
            acc[0][j] = __builtin_amdgcn_mfma_f32_16x16x32_bf16(af0, bf, acc[0][j], 0, 0, 0);
            acc[1][j] = __builtin_amdgcn_mfma_f32_16x16x32_bf16(af1, bf, acc[1][j], 0, 0, 0);
        }
    }
    // epilogue: skip + exact GELU -> Ybf
    unsigned short* Yb = Ybf + (size_t)h*BLn + (size_t)ct*128*LC;
    #pragma unroll
    for (int i = 0; i < 2; i++) {
        int m0 = w*32 + i*16 + e4;
        int sl = m0 >> 3, off = m0 & 7;
        #pragma unroll
        for (int j = 0; j < 8; j++) {
            int col = j*16 + l16;
            ushort4 u4 = *(const ushort4*)&Ul[col*128 + (sl ^ (col & 7))*8 + off];
            float uu[4] = {b2f(u4.x), b2f(u4.y), b2f(u4.z), b2f(u4.w)};
            unsigned short ov[4];
            #pragma unroll
            for (int e = 0; e < 4; e++) {
                float yv = acc[i][j][e] + dsk*uu[e];
                ov[e] = f2b(0.5f*yv*(1.f + erff(yv*0.70710678118f)));
            }
            *(ushort4*)&Yb[col*LC + m0] = make_ushort4(ov[0], ov[1], ov[2], ov[3]);
        }
    }
}

// ---------------- GEMM-C (MFMA): z = W*Y with in-kernel Y transpose (LDS),
//                  fused bias+GLU+residual; last layer fuses decoder ----------------
__global__ __launch_bounds__(512) void k_gC2(const unsigned short* __restrict__ Wb,
        const float* __restrict__ outb, const unsigned short* __restrict__ Ybf,
        unsigned short* __restrict__ hb, const float* __restrict__ dw,
        const float* __restrict__ db, float* __restrict__ outp, int doDec) {
    __shared__ __align__(16) unsigned char smem[34048];
    unsigned short* Bl = (unsigned short*)smem;      // [64 n][258 h], XOR-swizzled
    float* part = (float*)smem;                      // aliased: [64 n][33 groups]
    int nt = blockIdx.x;
    int n0 = nt*64;
    int tid = threadIdx.x;

    {
        int jn = (tid & 15) * 4;
        int hq = tid >> 4;          // 0..31
        #pragma unroll
        for (int hb8 = 0; hb8 < 8; hb8++) {
            int h = hb8*32 + hq;
            ushort4 v = *(const ushort4*)&Ybf[(size_t)h*BLn + n0 + jn];
            unsigned short vv[4] = {v.x, v.y, v.z, v.w};
            #pragma unroll
            for (int i = 0; i < 4; i++) {
                int row = jn + i;
                Bl[row*258 + (h ^ ((row & 7) << 3))] = vv[i];
            }
        }
    }
    __syncthreads();

    int w = tid >> 6, l = tid & 63;
    int l16 = l & 15, lk8 = (l >> 4) * 8, e4 = (l >> 4) * 4;
    int ra = w*32 + l16;
    int swz = (l16 & 7) << 3;
    f4v acc[4][4];
    #pragma unroll
    for (int i = 0; i < 4; i++)
        #pragma unroll
        for (int j = 0; j < 4; j++) acc[i][j] = (f4v){0.f,0.f,0.f,0.f};
    const unsigned short* W0 = Wb + ra*HH;
    const unsigned short* W1 = Wb + (ra+16)*HH;
    const unsigned short* W2 = Wb + (ra+256)*HH;
    const unsigned short* W3 = Wb + (ra+272)*HH;
    #pragma unroll
    for (int ks = 0; ks < 8; ks++) {
        int kk = ks*32 + lk8;
        s8v a0 = *(const s8v*)(W0 + kk);
        s8v a1 = *(const s8v*)(W1 + kk);
        s8v a2 = *(const s8v*)(W2 + kk);
        s8v a3 = *(const s8v*)(W3 + kk);
        s8v bfv[4];
        #pragma unroll
        for (int j = 0; j < 4; j++) {
            int row = j*16 + l16;
            bfv[j] = *(const s8v*)&Bl[row*258 + (kk ^ swz)];
        }
        #pragma unroll
        for (int j = 0; j < 4; j++) {
            acc[0][j] = __builtin_amdgcn_mfma_f32_16x16x32_bf16(a0, bfv[j], acc[0][j], 0, 0, 0);
            acc[1][j] = __builtin_amdgcn_mfma_f32_16x16x32_bf16(a1, bfv[j], acc[1][j], 0, 0, 0);
            acc[2][j] = __builtin_amdgcn_mfma_f32_16x16x32_bf16(a2, bfv[j], acc[2][j], 0, 0, 0);
            acc[3][j] = __builtin_amdgcn_mfma_f32_16x16x32_bf16(a3, bfv[j], acc[3][j], 0, 0, 0);
        }
    }

    float pj[4] = {0.f, 0.f, 0.f, 0.f};
    #pragma unroll
    for (int i = 0; i < 2; i++) {
        int ob = w*32 + i*16 + e4;
        #pragma unroll
        for (int e = 0; e < 4; e++) {
            int o = ob + e;
            float ba  = outb[o];
            float bb2 = outb[o + 256];
            float dwo = doDec ? dw[o] : 0.f;
            #pragma unroll
            for (int j = 0; j < 4; j++) {
                float za = acc[i][j][e] + ba;
                float zb = acc[i+2][j][e] + bb2;
                float sig = 1.f/(1.f + expf(-zb));
                unsigned short* hp = &hb[(size_t)o*BLn + n0 + j*16 + l16];
                float hnew = b2f(*hp) + za*sig;
                if (doDec) {
                    pj[j] = fmaf(dwo, hnew, pj[j]);
                } else {
                    *hp = f2b(hnew);
                }
            }
        }
    }

    if (doDec) {
        __syncthreads();
        int g32 = w*4 + (l >> 4);
        #pragma unroll
        for (int j = 0; j < 4; j++) {
            int nl = j*16 + l16;
            part[nl*33 + g32] = pj[j];
        }
        __syncthreads();
        if (tid < 64) {
            float s = db[0];
            #pragma unroll
            for (int g = 0; g < 32; g++) s += part[tid*33 + g];
            outp[n0 + tid] = s;
        }
    }
}

extern "C" void kernel_launch(void* const* d_in, const int* in_sizes, int n_in,
                              void* d_out, int out_size, void* d_ws, size_t ws_size,
                              hipStream_t stream) {
    (void)in_sizes; (void)n_in; (void)out_size; (void)ws_size;
    const float* x    = (const float*)d_in[0];
    const float* ew   = (const float*)d_in[1];
    const float* ldt  = (const float*)d_in[2];
    const float* Cp   = (const float*)d_in[3];
    const float* lAr  = (const float*)d_in[4];
    const float* Aimp = (const float*)d_in[5];
    const float* Dsk  = (const float*)d_in[6];
    const float* outw = (const float*)d_in[7];
    const float* outb = (const float*)d_in[8];
    const float* dw   = (const float*)d_in[9];
    const float* db   = (const float*)d_in[10];

    float* ws = (float*)d_ws;
    unsigned short* hb  = (unsigned short*)ws;                  // 33,554,432 bf16  [h][b][l]
    unsigned short* Ybf = (unsigned short*)(ws + 16777216UL);   // 33,554,432 bf16
    unsigned short* AstB= (unsigned short*)(ws + 33554432UL);   //  8,388,608 bf16
    unsigned short* AcvB= (unsigned short*)(ws + 37748736UL);   // 25,165,824 bf16
    unsigned short* Wbf = (unsigned short*)(ws + 50331648UL);   //    524,288 bf16
    float* pdta = ws + 50593792UL;                              //     65,536 f32
    float* pwlc = ws + 50659328UL;                              //     65,536 f32
    float* pcd2 = ws + 50724864UL;                              //     65,536 f32  end ~203 MB

    k_prep1<<<128, 256, 0, stream>>>(ldt, Cp, lAr, Aimp, pdta, pwlc, pcd2);
    k_bldAll<<<1024, 256, 0, stream>>>(pdta, pcd2, AstB, AcvB);
    k_prepW<<<2048, 256, 0, stream>>>(outw, Wbf);
    k_enc<<<4096, 256, 0, stream>>>(x, ew, hb);
    for (int layer = 0; layer < NLAY; layer++) {
        k_BG<<<dim3(8, 256), 256, 0, stream>>>(AstB + (size_t)layer*2097152,
                                               AcvB + (size_t)layer*6291456, hb,
                                               pwlc + layer*16384, pcd2 + layer*16384,
                                               Dsk + layer*HH, Ybf);
        k_gC2<<<2048, 512, 0, stream>>>(Wbf + layer*131072, outb + layer*512, Ybf, hb,
                                        dw, db, (float*)d_out, (layer == NLAY-1) ? 1 : 0);
    }
}